// Round 2
// baseline (1222.428 us; speedup 1.0000x reference)
//
#include <hip/hip_runtime.h>

// SpectralConvLayer: per-scale linear (x+spectral)@Ws concat -> ragged MHA
// (no key-padding mask: padded keys contribute exp(0)=1 to denom) -> out-proj
// -> BatchNorm(batch stats) -> ReLU.
// Round 2: fix batch dtype (harness passes integers as int32, NOT int64).

typedef __attribute__((ext_vector_type(8))) short frag8;      // 8 bf16 (4 VGPR)
typedef __attribute__((ext_vector_type(4))) float f32x4;
typedef __attribute__((ext_vector_type(8))) unsigned short ushort8;

#define NN 32768
#define NB 64
#define CIN 256
#define COUT 256
#define NHEAD 8
#define HD 32

#define BM 128
#define BN 64
#define BK 64
#define LDK 72   // +8 shorts pad: breaks pow2 LDS strides

__device__ inline unsigned short f2bf(float f) {
  unsigned u = __builtin_bit_cast(unsigned, f);
  u += 0x7FFFu + ((u >> 16) & 1u);          // RNE
  return (unsigned short)(u >> 16);
}
__device__ inline float bf2f(unsigned short h) {
  return __builtin_bit_cast(float, (unsigned)h << 16);
}

// ---------------- meta: counts / starts / max_nodes ----------------
__global__ void k_meta(const int* __restrict__ batch, int* __restrict__ meta) {
  __shared__ int cnt[NB];
  int t = threadIdx.x;
  if (t < NB) cnt[t] = 0;
  __syncthreads();
  for (int i = t; i < NN; i += 256) atomicAdd(&cnt[batch[i]], 1);
  __syncthreads();
  if (t == 0) {
    int run = 0, mx = 0;
    for (int b = 0; b < NB; ++b) {
      int c = cnt[b];
      meta[b] = c; meta[NB + b] = run; run += c; if (c > mx) mx = c;
    }
    meta[2 * NB] = mx;
  }
}

// ---------------- weight prep: fp32 -> bf16, B laid out as Bt[n][k] ----------------
// Ws[s][i][o] -> wst[s][o][i]  (transpose).  W_in[o][i] / W_out[o][i] already Bt.
__global__ void k_prep(const float* __restrict__ Ws, const float* __restrict__ Win,
                       const float* __restrict__ Wout,
                       unsigned short* __restrict__ wst, unsigned short* __restrict__ winb,
                       unsigned short* __restrict__ woutb) {
  int tid = blockIdx.x * 256 + threadIdx.x;
  if (tid < 4 * 64 * 256) {
    int s = tid >> 14, rem = tid & 16383, o = rem >> 8, i = rem & 255;
    wst[tid] = f2bf(Ws[((s * 256) + i) * 64 + o]);
  } else if (tid < 4 * 64 * 256 + 768 * 256) {
    int t2 = tid - 4 * 64 * 256;
    winb[t2] = f2bf(Win[t2]);
  } else if (tid < 4 * 64 * 256 + 768 * 256 + 256 * 256) {
    int t3 = tid - (4 * 64 * 256 + 768 * 256);
    woutb[t3] = f2bf(Wout[t3]);
  }
}

// ---------------- shared GEMM pieces ----------------
// A-frag: lane(m=l&15,q=l>>4) holds A[m][q*8+j]   (measured m118/m120)
// B-frag: lane(n=l&15,q)      holds B[q*8+j][n] = Bt[n][q*8+j]
// C/D   : lane holds D[q*4+reg][l&15]            (measured m89/m91)
__device__ inline void mfma_tile(const unsigned short (*As)[LDK],
                                 const unsigned short (*Bs)[LDK],
                                 f32x4 acc[2][4], int wave, int lane) {
  int m16 = lane & 15, quad = lane >> 4;
#pragma unroll
  for (int kk = 0; kk < 2; ++kk) {
    frag8 a[2], b[4];
#pragma unroll
    for (int mi = 0; mi < 2; ++mi)
      a[mi] = *(const frag8*)&As[wave * 32 + mi * 16 + m16][kk * 32 + quad * 8];
#pragma unroll
    for (int ni = 0; ni < 4; ++ni)
      b[ni] = *(const frag8*)&Bs[ni * 16 + m16][kk * 32 + quad * 8];
#pragma unroll
    for (int mi = 0; mi < 2; ++mi)
#pragma unroll
      for (int ni = 0; ni < 4; ++ni)
        acc[mi][ni] = __builtin_amdgcn_mfma_f32_16x16x32_bf16(a[mi], b[ni], acc[mi][ni], 0, 0, 0);
  }
}

__device__ inline void stage_B64(const unsigned short* __restrict__ Wt, int c0, int k0,
                                 unsigned short (*Bs)[LDK], int t) {
  int n = t & 63, seg = t >> 6;
  const unsigned short* src = Wt + (size_t)(c0 + n) * 256 + k0 + seg * 16;
  uint4 v0 = *(const uint4*)src;
  uint4 v1 = *(const uint4*)(src + 8);
  *(uint4*)&Bs[n][seg * 16] = v0;
  *(uint4*)&Bs[n][seg * 16 + 8] = v1;
}

__device__ inline void stage_A_bf(const unsigned short* __restrict__ A, int lda, int r0, int k0,
                                  unsigned short (*As)[LDK], int t) {
  int r = t >> 1, half = t & 1;
  const unsigned short* src = A + (size_t)(r0 + r) * lda + k0 + half * 32;
#pragma unroll
  for (int i = 0; i < 4; ++i) {
    uint4 v = *(const uint4*)(src + i * 8);
    *(uint4*)&As[r][half * 32 + i * 8] = v;
  }
}

// ---------------- scale-linear: h[n, s*64+o] = (x+spec_s)[n,:] @ Ws[s] + bs ----------------
__global__ __launch_bounds__(256) void k_scale(const float* __restrict__ x,
                                               const float* __restrict__ spec,
                                               const unsigned short* __restrict__ wst,
                                               const float* __restrict__ bs,
                                               unsigned short* __restrict__ h) {
  __shared__ unsigned short As[BM][LDK];
  __shared__ unsigned short Bs[BN][LDK];
  int t = threadIdx.x, lane = t & 63, wave = t >> 6;
  int r0 = blockIdx.x * BM, s = blockIdx.y;
  f32x4 z = {0.f, 0.f, 0.f, 0.f};
  f32x4 acc[2][4];
#pragma unroll
  for (int mi = 0; mi < 2; ++mi)
#pragma unroll
    for (int ni = 0; ni < 4; ++ni) acc[mi][ni] = z;

  const float* sb = spec + (size_t)s * NN * CIN;
  for (int k0 = 0; k0 < CIN; k0 += BK) {
    {  // fused A staging: fp32 x + spectral -> bf16 LDS
      int r = t >> 1, half = t & 1;
      const float* xs = x + (size_t)(r0 + r) * CIN + k0 + half * 32;
      const float* ss = sb + (size_t)(r0 + r) * CIN + k0 + half * 32;
#pragma unroll
      for (int i = 0; i < 8; ++i) {
        float4 xv = *(const float4*)(xs + i * 4);
        float4 sv = *(const float4*)(ss + i * 4);
        ushort4 o;
        o.x = f2bf(xv.x + sv.x); o.y = f2bf(xv.y + sv.y);
        o.z = f2bf(xv.z + sv.z); o.w = f2bf(xv.w + sv.w);
        *(ushort4*)&As[r][half * 32 + i * 4] = o;
      }
    }
    stage_B64(wst + (size_t)s * 64 * 256, 0, k0, Bs, t);
    __syncthreads();
    mfma_tile(As, Bs, acc, wave, lane);
    __syncthreads();
  }
  int m16 = lane & 15, quad = lane >> 4;
#pragma unroll
  for (int mi = 0; mi < 2; ++mi)
#pragma unroll
    for (int ni = 0; ni < 4; ++ni) {
      int col = ni * 16 + m16;
      float bias = bs[s * 64 + col];
#pragma unroll
      for (int r = 0; r < 4; ++r) {
        int row = r0 + wave * 32 + mi * 16 + quad * 4 + r;
        h[(size_t)row * COUT + s * 64 + col] = f2bf(acc[mi][ni][r] + bias);
      }
    }
}

// ---------------- generic bf16 GEMM: out[n, c0+col] = A[n,:] @ Bt^T + bias ----------------
template <int LDOUT, bool F32OUT>
__global__ __launch_bounds__(256) void k_lin(const unsigned short* __restrict__ A,
                                             const unsigned short* __restrict__ Wt,
                                             const float* __restrict__ bias,
                                             void* __restrict__ out) {
  __shared__ unsigned short As[BM][LDK];
  __shared__ unsigned short Bs[BN][LDK];
  int t = threadIdx.x, lane = t & 63, wave = t >> 6;
  int r0 = blockIdx.x * BM, c0 = blockIdx.y * BN;
  f32x4 z = {0.f, 0.f, 0.f, 0.f};
  f32x4 acc[2][4];
#pragma unroll
  for (int mi = 0; mi < 2; ++mi)
#pragma unroll
    for (int ni = 0; ni < 4; ++ni) acc[mi][ni] = z;

  for (int k0 = 0; k0 < 256; k0 += BK) {
    stage_A_bf(A, 256, r0, k0, As, t);
    stage_B64(Wt, c0, k0, Bs, t);
    __syncthreads();
    mfma_tile(As, Bs, acc, wave, lane);
    __syncthreads();
  }
  int m16 = lane & 15, quad = lane >> 4;
#pragma unroll
  for (int mi = 0; mi < 2; ++mi)
#pragma unroll
    for (int ni = 0; ni < 4; ++ni) {
      int col = c0 + ni * 16 + m16;
      float bv = bias[col];
#pragma unroll
      for (int r = 0; r < 4; ++r) {
        int row = r0 + wave * 32 + mi * 16 + quad * 4 + r;
        float v = acc[mi][ni][r] + bv;
        if constexpr (F32OUT)
          ((float*)out)[(size_t)row * LDOUT + col] = v;
        else
          ((unsigned short*)out)[(size_t)row * LDOUT + col] = f2bf(v);
      }
    }
}

// ---------------- ragged attention, one block per (graph, head) ----------------
// No max-subtraction (|s| bounded ~7): padded keys contribute exactly 1 each
// to the denominator -> add (max_nodes - c).
__global__ __launch_bounds__(256) void k_attn(const unsigned short* __restrict__ qkv,
                                              const int* __restrict__ meta,
                                              unsigned short* __restrict__ ctx) {
  int b = blockIdx.x >> 3, head = blockIdx.x & 7;
  int c = meta[b], st = meta[NB + b], M = meta[2 * NB];
  __shared__ float Ks[128][36];
  __shared__ float Vs[128][36];
  int t = threadIdx.x;
  float extra = (float)(M - c);
  const float SCALE = 0.17677669529663687f;  // 1/sqrt(32)

  for (int q0 = 0; q0 < c; q0 += 256) {
    int qi = q0 + t;
    bool valid = qi < c;
    float q[32], o[32];
    float l = 0.f;
#pragma unroll
    for (int d = 0; d < 32; ++d) o[d] = 0.f;
    if (valid) {
      const unsigned short* qp = qkv + (size_t)(st + qi) * 768 + head * 32;
#pragma unroll
      for (int seg = 0; seg < 4; ++seg) {
        ushort8 qv = *(const ushort8*)(qp + seg * 8);
#pragma unroll
        for (int i = 0; i < 8; ++i) q[seg * 8 + i] = bf2f(qv[i]) * SCALE;
      }
    }
    for (int k0 = 0; k0 < c; k0 += 128) {
      int jmax = min(128, c - k0);
      {  // stage K,V tile -> fp32 LDS
        int r = t >> 1, half = t & 1;
        if (r < jmax) {
          const unsigned short* kp =
              qkv + (size_t)(st + k0 + r) * 768 + 256 + head * 32 + half * 16;
          ushort8 k0v = *(const ushort8*)kp;
          ushort8 k1v = *(const ushort8*)(kp + 8);
          ushort8 v0v = *(const ushort8*)(kp + 256);
          ushort8 v1v = *(const ushort8*)(kp + 264);
#pragma unroll
          for (int i = 0; i < 8; ++i) {
            Ks[r][half * 16 + i] = bf2f(k0v[i]);
            Ks[r][half * 16 + 8 + i] = bf2f(k1v[i]);
            Vs[r][half * 16 + i] = bf2f(v0v[i]);
            Vs[r][half * 16 + 8 + i] = bf2f(v1v[i]);
          }
        }
      }
      __syncthreads();
      if (valid) {
        for (int j = 0; j < jmax; ++j) {
          float sdot = 0.f;
#pragma unroll
          for (int d4 = 0; d4 < 8; ++d4) {
            float4 kv = *(const float4*)&Ks[j][d4 * 4];
            sdot += q[d4 * 4 + 0] * kv.x + q[d4 * 4 + 1] * kv.y +
                    q[d4 * 4 + 2] * kv.z + q[d4 * 4 + 3] * kv.w;
          }
          float p = __expf(sdot);
          l += p;
#pragma unroll
          for (int d4 = 0; d4 < 8; ++d4) {
            float4 vv = *(const float4*)&Vs[j][d4 * 4];
            o[d4 * 4 + 0] += p * vv.x; o[d4 * 4 + 1] += p * vv.y;
            o[d4 * 4 + 2] += p * vv.z; o[d4 * 4 + 3] += p * vv.w;
          }
        }
      }
      __syncthreads();
    }
    if (valid) {
      float inv = 1.f / (l + extra);
      unsigned short* op = ctx + (size_t)(st + qi) * 256 + head * 32;
#pragma unroll
      for (int seg = 0; seg < 8; ++seg) {
        ushort4 ov;
        ov.x = f2bf(o[seg * 4 + 0] * inv); ov.y = f2bf(o[seg * 4 + 1] * inv);
        ov.z = f2bf(o[seg * 4 + 2] * inv); ov.w = f2bf(o[seg * 4 + 3] * inv);
        *(ushort4*)(op + seg * 4) = ov;
      }
    }
  }
}

// ---------------- BatchNorm: stats, finalize, apply+ReLU ----------------
__global__ __launch_bounds__(256) void k_bn_stats(const float* __restrict__ h,
                                                  float* __restrict__ sums) {
  int ch = threadIdx.x;
  int r0 = blockIdx.x * 512;
  float s = 0.f, s2 = 0.f;
  for (int r = 0; r < 512; ++r) {
    float v = h[(size_t)(r0 + r) * 256 + ch];
    s += v; s2 += v * v;
  }
  atomicAdd(&sums[ch], s);
  atomicAdd(&sums[256 + ch], s2);
}

__global__ void k_bn_final(const float* __restrict__ sums, const float* __restrict__ gamma,
                           const float* __restrict__ beta, float* __restrict__ bnp) {
  int c = threadIdx.x;
  float mean = sums[c] * (1.0f / NN);
  float var = sums[256 + c] * (1.0f / NN) - mean * mean;  // biased, ddof=0
  float sc = rsqrtf(var + 1e-5f) * gamma[c];
  bnp[c] = sc;
  bnp[256 + c] = beta[c] - mean * sc;
}

__global__ __launch_bounds__(256) void k_bn_apply(const float* __restrict__ h,
                                                  const float* __restrict__ bnp,
                                                  float* __restrict__ out) {
  size_t i4 = (size_t)blockIdx.x * 256 + threadIdx.x;
  float4 v = *(const float4*)(h + i4 * 4);
  int c = (int)((i4 * 4) & 255);
  float4 sc = *(const float4*)(bnp + c);
  float4 sh = *(const float4*)(bnp + 256 + c);
  float4 r;
  r.x = fmaxf(v.x * sc.x + sh.x, 0.f);
  r.y = fmaxf(v.y * sc.y + sh.y, 0.f);
  r.z = fmaxf(v.z * sc.z + sh.z, 0.f);
  r.w = fmaxf(v.w * sc.w + sh.w, 0.f);
  *(float4*)(out + i4 * 4) = r;
}

extern "C" void kernel_launch(void* const* d_in, const int* in_sizes, int n_in,
                              void* d_out, int out_size, void* d_ws, size_t ws_size,
                              hipStream_t stream) {
  const float* x      = (const float*)d_in[0];
  const float* spec   = (const float*)d_in[1];
  const float* Ws     = (const float*)d_in[2];
  const float* bs     = (const float*)d_in[3];
  const float* Win    = (const float*)d_in[4];
  const float* b_in   = (const float*)d_in[5];
  const float* Wout   = (const float*)d_in[6];
  const float* b_out  = (const float*)d_in[7];
  const float* gamma  = (const float*)d_in[8];
  const float* beta   = (const float*)d_in[9];
  const int* batch    = (const int*)d_in[10];   // harness passes integers as int32
  float* out = (float*)d_out;

  char* w = (char*)d_ws;
  size_t off = 0;
  auto alloc = [&](size_t bytes) -> void* {
    off = (off + 255) & ~(size_t)255;
    void* p = w + off; off += bytes; return p;
  };
  int* meta             = (int*)alloc(129 * sizeof(int));
  unsigned short* wst   = (unsigned short*)alloc((size_t)4 * 64 * 256 * 2);
  unsigned short* winb  = (unsigned short*)alloc((size_t)768 * 256 * 2);
  unsigned short* woutb = (unsigned short*)alloc((size_t)256 * 256 * 2);
  float* sums           = (float*)alloc(512 * 4);
  float* bnp            = (float*)alloc(512 * 4);
  unsigned short* h     = (unsigned short*)alloc((size_t)NN * 256 * 2);
  unsigned short* qkv   = (unsigned short*)alloc((size_t)NN * 768 * 2);
  unsigned short* ctx   = (unsigned short*)alloc((size_t)NN * 256 * 2);
  float* hatt           = (float*)alloc((size_t)NN * 256 * 4);

  hipMemsetAsync(sums, 0, 512 * 4, stream);
  k_meta<<<1, 256, 0, stream>>>(batch, meta);
  k_prep<<<1280, 256, 0, stream>>>(Ws, Win, Wout, wst, winb, woutb);
  k_scale<<<dim3(NN / BM, 4), 256, 0, stream>>>(x, spec, wst, bs, h);
  k_lin<768, false><<<dim3(NN / BM, 12), 256, 0, stream>>>(h, winb, b_in, qkv);
  k_attn<<<NB * NHEAD, 256, 0, stream>>>(qkv, meta, ctx);
  k_lin<256, true><<<dim3(NN / BM, 4), 256, 0, stream>>>(ctx, woutb, b_out, hatt);
  k_bn_stats<<<64, 256, 0, stream>>>(hatt, sums);
  k_bn_final<<<1, 256, 0, stream>>>(sums, gamma, beta, bnp);
  k_bn_apply<<<NN * 256 / 1024, 256, 0, stream>>>(hatt, bnp, out);
}

// Round 3
// 480.909 us; speedup vs baseline: 2.5419x; 2.5419x over previous
//
#include <hip/hip_runtime.h>

// SpectralConvLayer: per-scale linear (x+spectral)@Ws concat -> ragged MHA
// (no key-padding mask: padded keys contribute exp(0)=1 to denom) -> out-proj
// -> BatchNorm(batch stats) -> ReLU.
// Round 3: MFMA flash-style attention (head_dim 32 == MFMA K), grid (B*H, 8 qchunks).

typedef __attribute__((ext_vector_type(8))) short frag8;      // 8 bf16 (4 VGPR)
typedef __attribute__((ext_vector_type(4))) float f32x4;
typedef __attribute__((ext_vector_type(8))) unsigned short ushort8;

#define NN 32768
#define NB 64
#define CIN 256
#define COUT 256
#define NHEAD 8
#define HD 32

#define BM 128
#define BN 64
#define BK 64
#define LDK 72   // +8 shorts pad: breaks pow2 LDS strides

__device__ inline unsigned short f2bf(float f) {
  unsigned u = __builtin_bit_cast(unsigned, f);
  u += 0x7FFFu + ((u >> 16) & 1u);          // RNE
  return (unsigned short)(u >> 16);
}
__device__ inline float bf2f(unsigned short h) {
  return __builtin_bit_cast(float, (unsigned)h << 16);
}

// ---------------- meta: counts / starts / max_nodes ----------------
__global__ void k_meta(const int* __restrict__ batch, int* __restrict__ meta) {
  __shared__ int cnt[NB];
  int t = threadIdx.x;
  if (t < NB) cnt[t] = 0;
  __syncthreads();
  for (int i = t; i < NN; i += 256) atomicAdd(&cnt[batch[i]], 1);
  __syncthreads();
  if (t == 0) {
    int run = 0, mx = 0;
    for (int b = 0; b < NB; ++b) {
      int c = cnt[b];
      meta[b] = c; meta[NB + b] = run; run += c; if (c > mx) mx = c;
    }
    meta[2 * NB] = mx;
  }
}

// ---------------- weight prep: fp32 -> bf16, B laid out as Bt[n][k] ----------------
__global__ void k_prep(const float* __restrict__ Ws, const float* __restrict__ Win,
                       const float* __restrict__ Wout,
                       unsigned short* __restrict__ wst, unsigned short* __restrict__ winb,
                       unsigned short* __restrict__ woutb) {
  int tid = blockIdx.x * 256 + threadIdx.x;
  if (tid < 4 * 64 * 256) {
    int s = tid >> 14, rem = tid & 16383, o = rem >> 8, i = rem & 255;
    wst[tid] = f2bf(Ws[((s * 256) + i) * 64 + o]);
  } else if (tid < 4 * 64 * 256 + 768 * 256) {
    int t2 = tid - 4 * 64 * 256;
    winb[t2] = f2bf(Win[t2]);
  } else if (tid < 4 * 64 * 256 + 768 * 256 + 256 * 256) {
    int t3 = tid - (4 * 64 * 256 + 768 * 256);
    woutb[t3] = f2bf(Wout[t3]);
  }
}

// ---------------- shared GEMM pieces ----------------
// A-frag: lane(m=l&15,q=l>>4) holds A[m][q*8+j]
// B-frag: lane(n=l&15,q)      holds B[q*8+j][n] = Bt[n][q*8+j]
// C/D   : lane holds D[q*4+reg][l&15]            (measured m89/m91)
__device__ inline void mfma_tile(const unsigned short (*As)[LDK],
                                 const unsigned short (*Bs)[LDK],
                                 f32x4 acc[2][4], int wave, int lane) {
  int m16 = lane & 15, quad = lane >> 4;
#pragma unroll
  for (int kk = 0; kk < 2; ++kk) {
    frag8 a[2], b[4];
#pragma unroll
    for (int mi = 0; mi < 2; ++mi)
      a[mi] = *(const frag8*)&As[wave * 32 + mi * 16 + m16][kk * 32 + quad * 8];
#pragma unroll
    for (int ni = 0; ni < 4; ++ni)
      b[ni] = *(const frag8*)&Bs[ni * 16 + m16][kk * 32 + quad * 8];
#pragma unroll
    for (int mi = 0; mi < 2; ++mi)
#pragma unroll
      for (int ni = 0; ni < 4; ++ni)
        acc[mi][ni] = __builtin_amdgcn_mfma_f32_16x16x32_bf16(a[mi], b[ni], acc[mi][ni], 0, 0, 0);
  }
}

__device__ inline void stage_B64(const unsigned short* __restrict__ Wt, int c0, int k0,
                                 unsigned short (*Bs)[LDK], int t) {
  int n = t & 63, seg = t >> 6;
  const unsigned short* src = Wt + (size_t)(c0 + n) * 256 + k0 + seg * 16;
  uint4 v0 = *(const uint4*)src;
  uint4 v1 = *(const uint4*)(src + 8);
  *(uint4*)&Bs[n][seg * 16] = v0;
  *(uint4*)&Bs[n][seg * 16 + 8] = v1;
}

__device__ inline void stage_A_bf(const unsigned short* __restrict__ A, int lda, int r0, int k0,
                                  unsigned short (*As)[LDK], int t) {
  int r = t >> 1, half = t & 1;
  const unsigned short* src = A + (size_t)(r0 + r) * lda + k0 + half * 32;
#pragma unroll
  for (int i = 0; i < 4; ++i) {
    uint4 v = *(const uint4*)(src + i * 8);
    *(uint4*)&As[r][half * 32 + i * 8] = v;
  }
}

// ---------------- scale-linear: h[n, s*64+o] = (x+spec_s)[n,:] @ Ws[s] + bs ----------------
__global__ __launch_bounds__(256) void k_scale(const float* __restrict__ x,
                                               const float* __restrict__ spec,
                                               const unsigned short* __restrict__ wst,
                                               const float* __restrict__ bs,
                                               unsigned short* __restrict__ h) {
  __shared__ unsigned short As[BM][LDK];
  __shared__ unsigned short Bs[BN][LDK];
  int t = threadIdx.x, lane = t & 63, wave = t >> 6;
  int r0 = blockIdx.x * BM, s = blockIdx.y;
  f32x4 z = {0.f, 0.f, 0.f, 0.f};
  f32x4 acc[2][4];
#pragma unroll
  for (int mi = 0; mi < 2; ++mi)
#pragma unroll
    for (int ni = 0; ni < 4; ++ni) acc[mi][ni] = z;

  const float* sb = spec + (size_t)s * NN * CIN;
  for (int k0 = 0; k0 < CIN; k0 += BK) {
    {  // fused A staging: fp32 x + spectral -> bf16 LDS
      int r = t >> 1, half = t & 1;
      const float* xs = x + (size_t)(r0 + r) * CIN + k0 + half * 32;
      const float* ss = sb + (size_t)(r0 + r) * CIN + k0 + half * 32;
#pragma unroll
      for (int i = 0; i < 8; ++i) {
        float4 xv = *(const float4*)(xs + i * 4);
        float4 sv = *(const float4*)(ss + i * 4);
        ushort4 o;
        o.x = f2bf(xv.x + sv.x); o.y = f2bf(xv.y + sv.y);
        o.z = f2bf(xv.z + sv.z); o.w = f2bf(xv.w + sv.w);
        *(ushort4*)&As[r][half * 32 + i * 4] = o;
      }
    }
    stage_B64(wst + (size_t)s * 64 * 256, 0, k0, Bs, t);
    __syncthreads();
    mfma_tile(As, Bs, acc, wave, lane);
    __syncthreads();
  }
  int m16 = lane & 15, quad = lane >> 4;
#pragma unroll
  for (int mi = 0; mi < 2; ++mi)
#pragma unroll
    for (int ni = 0; ni < 4; ++ni) {
      int col = ni * 16 + m16;
      float bias = bs[s * 64 + col];
#pragma unroll
      for (int r = 0; r < 4; ++r) {
        int row = r0 + wave * 32 + mi * 16 + quad * 4 + r;
        h[(size_t)row * COUT + s * 64 + col] = f2bf(acc[mi][ni][r] + bias);
      }
    }
}

// ---------------- generic bf16 GEMM: out[n, c0+col] = A[n,:] @ Bt^T + bias ----------------
template <int LDOUT, bool F32OUT>
__global__ __launch_bounds__(256) void k_lin(const unsigned short* __restrict__ A,
                                             const unsigned short* __restrict__ Wt,
                                             const float* __restrict__ bias,
                                             void* __restrict__ out) {
  __shared__ unsigned short As[BM][LDK];
  __shared__ unsigned short Bs[BN][LDK];
  int t = threadIdx.x, lane = t & 63, wave = t >> 6;
  int r0 = blockIdx.x * BM, c0 = blockIdx.y * BN;
  f32x4 z = {0.f, 0.f, 0.f, 0.f};
  f32x4 acc[2][4];
#pragma unroll
  for (int mi = 0; mi < 2; ++mi)
#pragma unroll
    for (int ni = 0; ni < 4; ++ni) acc[mi][ni] = z;

  for (int k0 = 0; k0 < 256; k0 += BK) {
    stage_A_bf(A, 256, r0, k0, As, t);
    stage_B64(Wt, c0, k0, Bs, t);
    __syncthreads();
    mfma_tile(As, Bs, acc, wave, lane);
    __syncthreads();
  }
  int m16 = lane & 15, quad = lane >> 4;
#pragma unroll
  for (int mi = 0; mi < 2; ++mi)
#pragma unroll
    for (int ni = 0; ni < 4; ++ni) {
      int col = c0 + ni * 16 + m16;
      float bv = bias[col];
#pragma unroll
      for (int r = 0; r < 4; ++r) {
        int row = r0 + wave * 32 + mi * 16 + quad * 4 + r;
        float v = acc[mi][ni][r] + bv;
        if constexpr (F32OUT)
          ((float*)out)[(size_t)row * LDOUT + col] = v;
        else
          ((unsigned short*)out)[(size_t)row * LDOUT + col] = f2bf(v);
      }
    }
}

// ---------------- MFMA flash attention ----------------
// Block = (graph*8+head, qchunk of 128). 4 waves x 32 q-rows each.
// S-tile: A=Q[16x32] (direct 16B global frag), B=K (direct 16B global frag),
// one 16x16x32 MFMA per 16x16 score tile (head_dim 32 == MFMA K).
// P: C-layout -> LDS -> A-layout (m120-verified round trip). V staged transposed.
// No max-subtraction (|s| bounded); padded keys add exactly 1 each -> +(M-c).
__global__ __launch_bounds__(256) void k_attn_mfma(const unsigned short* __restrict__ qkv,
                                                   const int* __restrict__ meta,
                                                   unsigned short* __restrict__ ctx) {
  int b = blockIdx.x >> 3, head = blockIdx.x & 7;
  int c = meta[b], st = meta[NB + b], M = meta[2 * NB];
  int q0 = blockIdx.y * 128;
  if (q0 >= c) return;

  __shared__ unsigned short Vt[32][40];      // V^T tile: [d][key], +8 pad
  __shared__ unsigned short Pl[4][32][40];   // per-wave P: [qrow 0..31][key 0..31]

  int t = threadIdx.x, lane = t & 63, wave = t >> 6;
  int m16 = lane & 15, quad = lane >> 4;
  const float SCALE = 0.17677669529663687f;  // 1/sqrt(32)
  float extra = (float)(M - c);

  // Q fragments: wave covers rows qbase..qbase+31 (2 groups of 16)
  int qbase = q0 + wave * 32;
  frag8 qf[2];
#pragma unroll
  for (int qg = 0; qg < 2; ++qg) {
    int qrow = qbase + qg * 16 + m16;  // may exceed c: garbage, discarded at store
    qf[qg] = *(const frag8*)(qkv + (size_t)(st + qrow) * 768 + head * 32 + quad * 8);
  }

  f32x4 zz = {0.f, 0.f, 0.f, 0.f};
  f32x4 O[2][2];
  float lp[2][4];
#pragma unroll
  for (int qg = 0; qg < 2; ++qg) {
    O[qg][0] = zz; O[qg][1] = zz;
#pragma unroll
    for (int r = 0; r < 4; ++r) lp[qg][r] = 0.f;
  }

  for (int kt = 0; kt < c; kt += 32) {
    {  // stage V^T tile cooperatively (keys >= c carry garbage; masked via p=0)
      int key = t >> 3, ds = (t & 7) * 4;
      ushort4 v = *(const ushort4*)(qkv + (size_t)(st + kt + key) * 768 + 512 + head * 32 + ds);
      Vt[ds + 0][key] = v.x; Vt[ds + 1][key] = v.y;
      Vt[ds + 2][key] = v.z; Vt[ds + 3][key] = v.w;
    }
    __syncthreads();

    // K fragments (2 halves of the 32-key tile), direct from global
    frag8 kf[2];
#pragma unroll
    for (int hf = 0; hf < 2; ++hf) {
      int krow = kt + hf * 16 + m16;
      kf[hf] = *(const frag8*)(qkv + (size_t)(st + krow) * 768 + 256 + head * 32 + quad * 8);
    }

    // S = Q K^T -> p = exp(S*scale) -> per-wave LDS (transpose to A-layout)
#pragma unroll
    for (int qg = 0; qg < 2; ++qg)
#pragma unroll
      for (int hf = 0; hf < 2; ++hf) {
        f32x4 s = __builtin_amdgcn_mfma_f32_16x16x32_bf16(qf[qg], kf[hf], zz, 0, 0, 0);
        int key = kt + hf * 16 + m16;
        float msk = (key < c) ? 1.f : 0.f;
#pragma unroll
        for (int r = 0; r < 4; ++r) {
          float p = msk * __expf(s[r] * SCALE);
          lp[qg][r] += p;
          Pl[wave][qg * 16 + quad * 4 + r][hf * 16 + m16] = f2bf(p);
        }
      }
    __syncthreads();

    // PV: A = P (LDS, A-layout), B = V via Vt
    frag8 vf[2];
#pragma unroll
    for (int dh = 0; dh < 2; ++dh)
      vf[dh] = *(const frag8*)&Vt[dh * 16 + m16][quad * 8];
#pragma unroll
    for (int qg = 0; qg < 2; ++qg) {
      frag8 pf = *(const frag8*)&Pl[wave][qg * 16 + m16][quad * 8];
#pragma unroll
      for (int dh = 0; dh < 2; ++dh)
        O[qg][dh] = __builtin_amdgcn_mfma_f32_16x16x32_bf16(pf, vf[dh], O[qg][dh], 0, 0, 0);
    }
    __syncthreads();
  }

  // row-sum of lp across the 16 lanes sharing a quad
#pragma unroll
  for (int qg = 0; qg < 2; ++qg)
#pragma unroll
    for (int r = 0; r < 4; ++r) {
      float v = lp[qg][r];
      v += __shfl_xor(v, 1, 16);
      v += __shfl_xor(v, 2, 16);
      v += __shfl_xor(v, 4, 16);
      v += __shfl_xor(v, 8, 16);
      lp[qg][r] = v;
    }

#pragma unroll
  for (int qg = 0; qg < 2; ++qg)
#pragma unroll
    for (int r = 0; r < 4; ++r) {
      int qrow = qbase + qg * 16 + quad * 4 + r;
      if (qrow < c) {
        float inv = 1.f / (lp[qg][r] + extra);
        unsigned short* op = ctx + (size_t)(st + qrow) * 256 + head * 32;
        op[m16] = f2bf(O[qg][0][r] * inv);
        op[16 + m16] = f2bf(O[qg][1][r] * inv);
      }
    }
}

// ---------------- BatchNorm: stats, finalize, apply+ReLU ----------------
__global__ __launch_bounds__(256) void k_bn_stats(const float* __restrict__ h,
                                                  float* __restrict__ sums) {
  int ch = threadIdx.x;
  int r0 = blockIdx.x * 512;
  float s = 0.f, s2 = 0.f;
  for (int r = 0; r < 512; ++r) {
    float v = h[(size_t)(r0 + r) * 256 + ch];
    s += v; s2 += v * v;
  }
  atomicAdd(&sums[ch], s);
  atomicAdd(&sums[256 + ch], s2);
}

__global__ void k_bn_final(const float* __restrict__ sums, const float* __restrict__ gamma,
                           const float* __restrict__ beta, float* __restrict__ bnp) {
  int c = threadIdx.x;
  float mean = sums[c] * (1.0f / NN);
  float var = sums[256 + c] * (1.0f / NN) - mean * mean;  // biased, ddof=0
  float sc = rsqrtf(var + 1e-5f) * gamma[c];
  bnp[c] = sc;
  bnp[256 + c] = beta[c] - mean * sc;
}

__global__ __launch_bounds__(256) void k_bn_apply(const float* __restrict__ h,
                                                  const float* __restrict__ bnp,
                                                  float* __restrict__ out) {
  size_t i4 = (size_t)blockIdx.x * 256 + threadIdx.x;
  float4 v = *(const float4*)(h + i4 * 4);
  int c = (int)((i4 * 4) & 255);
  float4 sc = *(const float4*)(bnp + c);
  float4 sh = *(const float4*)(bnp + 256 + c);
  float4 r;
  r.x = fmaxf(v.x * sc.x + sh.x, 0.f);
  r.y = fmaxf(v.y * sc.y + sh.y, 0.f);
  r.z = fmaxf(v.z * sc.z + sh.z, 0.f);
  r.w = fmaxf(v.w * sc.w + sh.w, 0.f);
  *(float4*)(out + i4 * 4) = r;
}

extern "C" void kernel_launch(void* const* d_in, const int* in_sizes, int n_in,
                              void* d_out, int out_size, void* d_ws, size_t ws_size,
                              hipStream_t stream) {
  const float* x      = (const float*)d_in[0];
  const float* spec   = (const float*)d_in[1];
  const float* Ws     = (const float*)d_in[2];
  const float* bs     = (const float*)d_in[3];
  const float* Win    = (const float*)d_in[4];
  const float* b_in   = (const float*)d_in[5];
  const float* Wout   = (const float*)d_in[6];
  const float* b_out  = (const float*)d_in[7];
  const float* gamma  = (const float*)d_in[8];
  const float* beta   = (const float*)d_in[9];
  const int* batch    = (const int*)d_in[10];   // harness passes integers as int32
  float* out = (float*)d_out;

  char* w = (char*)d_ws;
  size_t off = 0;
  auto alloc = [&](size_t bytes) -> void* {
    off = (off + 255) & ~(size_t)255;
    void* p = w + off; off += bytes; return p;
  };
  int* meta             = (int*)alloc(129 * sizeof(int));
  unsigned short* wst   = (unsigned short*)alloc((size_t)4 * 64 * 256 * 2);
  unsigned short* winb  = (unsigned short*)alloc((size_t)768 * 256 * 2);
  unsigned short* woutb = (unsigned short*)alloc((size_t)256 * 256 * 2);
  float* sums           = (float*)alloc(512 * 4);
  float* bnp            = (float*)alloc(512 * 4);
  unsigned short* h     = (unsigned short*)alloc((size_t)NN * 256 * 2);
  unsigned short* qkv   = (unsigned short*)alloc((size_t)NN * 768 * 2);
  unsigned short* ctx   = (unsigned short*)alloc((size_t)NN * 256 * 2);
  float* hatt           = (float*)alloc((size_t)NN * 256 * 4);

  hipMemsetAsync(sums, 0, 512 * 4, stream);
  k_meta<<<1, 256, 0, stream>>>(batch, meta);
  k_prep<<<1280, 256, 0, stream>>>(Ws, Win, Wout, wst, winb, woutb);
  k_scale<<<dim3(NN / BM, 4), 256, 0, stream>>>(x, spec, wst, bs, h);
  k_lin<768, false><<<dim3(NN / BM, 12), 256, 0, stream>>>(h, winb, b_in, qkv);
  k_attn_mfma<<<dim3(NB * NHEAD, 8), 256, 0, stream>>>(qkv, meta, ctx);
  k_lin<256, true><<<dim3(NN / BM, 4), 256, 0, stream>>>(ctx, woutb, b_out, hatt);
  k_bn_stats<<<64, 256, 0, stream>>>(hatt, sums);
  k_bn_final<<<1, 256, 0, stream>>>(sums, gamma, beta, bnp);
  k_bn_apply<<<NN * 256 / 1024, 256, 0, stream>>>(hatt, bnp, out);
}

// Round 4
// 454.947 us; speedup vs baseline: 2.6870x; 1.0571x over previous
//
#include <hip/hip_runtime.h>

// SpectralConvLayer: per-scale linear (x+spectral)@Ws concat -> ragged MHA
// (no key-padding mask: padded keys contribute exp(0)=1 to denom) -> out-proj
// -> BatchNorm(batch stats) -> ReLU.
// Round 4: attn KT=128 (3 barriers/128 keys vs 8), bn_stats fused into out-proj
// epilogue, parallel boundary-based meta.

typedef __attribute__((ext_vector_type(8))) short frag8;      // 8 bf16 (4 VGPR)
typedef __attribute__((ext_vector_type(4))) float f32x4;
typedef __attribute__((ext_vector_type(8))) unsigned short ushort8;

#define NN 32768
#define NB 64
#define CIN 256
#define COUT 256
#define NHEAD 8
#define HD 32

#define BM 128
#define BN 64
#define BK 64
#define LDK 72   // +8 shorts pad: breaks pow2 LDS strides
#define KT 128   // attention key-tile

__device__ inline unsigned short f2bf(float f) {
  unsigned u = __builtin_bit_cast(unsigned, f);
  u += 0x7FFFu + ((u >> 16) & 1u);          // RNE
  return (unsigned short)(u >> 16);
}
__device__ inline float bf2f(unsigned short h) {
  return __builtin_bit_cast(float, (unsigned)h << 16);
}

// ---------------- meta: batch sorted -> starts via boundaries ----------------
__global__ void k_bounds(const int* __restrict__ batch, int* __restrict__ meta) {
  int i = blockIdx.x * 256 + threadIdx.x;
  if (i >= NN) return;
  int v = batch[i];
  int prev = (i == 0) ? -1 : batch[i - 1];
  for (int bb = prev + 1; bb <= v; ++bb) meta[NB + bb] = i;  // starts
}
__global__ void k_meta2(int* __restrict__ meta) {
  __shared__ int mx[NB];
  int b = threadIdx.x;  // 64 threads
  int s = meta[NB + b];
  int e = (b == 63) ? NN : meta[NB + b + 1];
  meta[b] = e - s;
  mx[b] = e - s;
  __syncthreads();
  if (b == 0) {
    int m = 0;
    for (int j = 0; j < NB; ++j) m = max(m, mx[j]);
    meta[2 * NB] = m;
  }
}

// ---------------- weight prep: fp32 -> bf16, B laid out as Bt[n][k] ----------------
__global__ void k_prep(const float* __restrict__ Ws, const float* __restrict__ Win,
                       const float* __restrict__ Wout,
                       unsigned short* __restrict__ wst, unsigned short* __restrict__ winb,
                       unsigned short* __restrict__ woutb) {
  int tid = blockIdx.x * 256 + threadIdx.x;
  if (tid < 4 * 64 * 256) {
    int s = tid >> 14, rem = tid & 16383, o = rem >> 8, i = rem & 255;
    wst[tid] = f2bf(Ws[((s * 256) + i) * 64 + o]);
  } else if (tid < 4 * 64 * 256 + 768 * 256) {
    int t2 = tid - 4 * 64 * 256;
    winb[t2] = f2bf(Win[t2]);
  } else if (tid < 4 * 64 * 256 + 768 * 256 + 256 * 256) {
    int t3 = tid - (4 * 64 * 256 + 768 * 256);
    woutb[t3] = f2bf(Wout[t3]);
  }
}

// ---------------- shared GEMM pieces ----------------
// A-frag: lane(m=l&15,q=l>>4) holds A[m][q*8+j]
// B-frag: lane(n=l&15,q)      holds B[q*8+j][n] = Bt[n][q*8+j]
// C/D   : lane holds D[q*4+reg][l&15]            (measured m89/m91)
__device__ inline void mfma_tile(const unsigned short (*As)[LDK],
                                 const unsigned short (*Bs)[LDK],
                                 f32x4 acc[2][4], int wave, int lane) {
  int m16 = lane & 15, quad = lane >> 4;
#pragma unroll
  for (int kk = 0; kk < 2; ++kk) {
    frag8 a[2], b[4];
#pragma unroll
    for (int mi = 0; mi < 2; ++mi)
      a[mi] = *(const frag8*)&As[wave * 32 + mi * 16 + m16][kk * 32 + quad * 8];
#pragma unroll
    for (int ni = 0; ni < 4; ++ni)
      b[ni] = *(const frag8*)&Bs[ni * 16 + m16][kk * 32 + quad * 8];
#pragma unroll
    for (int mi = 0; mi < 2; ++mi)
#pragma unroll
      for (int ni = 0; ni < 4; ++ni)
        acc[mi][ni] = __builtin_amdgcn_mfma_f32_16x16x32_bf16(a[mi], b[ni], acc[mi][ni], 0, 0, 0);
  }
}

__device__ inline void stage_B64(const unsigned short* __restrict__ Wt, int c0, int k0,
                                 unsigned short (*Bs)[LDK], int t) {
  int n = t & 63, seg = t >> 6;
  const unsigned short* src = Wt + (size_t)(c0 + n) * 256 + k0 + seg * 16;
  uint4 v0 = *(const uint4*)src;
  uint4 v1 = *(const uint4*)(src + 8);
  *(uint4*)&Bs[n][seg * 16] = v0;
  *(uint4*)&Bs[n][seg * 16 + 8] = v1;
}

__device__ inline void stage_A_bf(const unsigned short* __restrict__ A, int lda, int r0, int k0,
                                  unsigned short (*As)[LDK], int t) {
  int r = t >> 1, half = t & 1;
  const unsigned short* src = A + (size_t)(r0 + r) * lda + k0 + half * 32;
#pragma unroll
  for (int i = 0; i < 4; ++i) {
    uint4 v = *(const uint4*)(src + i * 8);
    *(uint4*)&As[r][half * 32 + i * 8] = v;
  }
}

// ---------------- scale-linear: h[n, s*64+o] = (x+spec_s)[n,:] @ Ws[s] + bs ----------------
__global__ __launch_bounds__(256) void k_scale(const float* __restrict__ x,
                                               const float* __restrict__ spec,
                                               const unsigned short* __restrict__ wst,
                                               const float* __restrict__ bs,
                                               unsigned short* __restrict__ h) {
  __shared__ unsigned short As[BM][LDK];
  __shared__ unsigned short Bs[BN][LDK];
  int t = threadIdx.x, lane = t & 63, wave = t >> 6;
  int r0 = blockIdx.x * BM, s = blockIdx.y;
  f32x4 z = {0.f, 0.f, 0.f, 0.f};
  f32x4 acc[2][4];
#pragma unroll
  for (int mi = 0; mi < 2; ++mi)
#pragma unroll
    for (int ni = 0; ni < 4; ++ni) acc[mi][ni] = z;

  const float* sb = spec + (size_t)s * NN * CIN;
  for (int k0 = 0; k0 < CIN; k0 += BK) {
    {  // fused A staging: fp32 x + spectral -> bf16 LDS
      int r = t >> 1, half = t & 1;
      const float* xs = x + (size_t)(r0 + r) * CIN + k0 + half * 32;
      const float* ss = sb + (size_t)(r0 + r) * CIN + k0 + half * 32;
#pragma unroll
      for (int i = 0; i < 8; ++i) {
        float4 xv = *(const float4*)(xs + i * 4);
        float4 sv = *(const float4*)(ss + i * 4);
        ushort4 o;
        o.x = f2bf(xv.x + sv.x); o.y = f2bf(xv.y + sv.y);
        o.z = f2bf(xv.z + sv.z); o.w = f2bf(xv.w + sv.w);
        *(ushort4*)&As[r][half * 32 + i * 4] = o;
      }
    }
    stage_B64(wst + (size_t)s * 64 * 256, 0, k0, Bs, t);
    __syncthreads();
    mfma_tile(As, Bs, acc, wave, lane);
    __syncthreads();
  }
  int m16 = lane & 15, quad = lane >> 4;
#pragma unroll
  for (int mi = 0; mi < 2; ++mi)
#pragma unroll
    for (int ni = 0; ni < 4; ++ni) {
      int col = ni * 16 + m16;
      float bias = bs[s * 64 + col];
#pragma unroll
      for (int r = 0; r < 4; ++r) {
        int row = r0 + wave * 32 + mi * 16 + quad * 4 + r;
        h[(size_t)row * COUT + s * 64 + col] = f2bf(acc[mi][ni][r] + bias);
      }
    }
}

// ------- generic bf16 GEMM; STATS fuses BatchNorm sum/sumsq reduction -------
template <int LDOUT, bool F32OUT, bool STATS>
__global__ __launch_bounds__(256) void k_lin(const unsigned short* __restrict__ A,
                                             const unsigned short* __restrict__ Wt,
                                             const float* __restrict__ bias,
                                             void* __restrict__ out,
                                             float* __restrict__ sums) {
  __shared__ unsigned short As[BM][LDK];
  __shared__ unsigned short Bs[BN][LDK];
  int t = threadIdx.x, lane = t & 63, wave = t >> 6;
  int r0 = blockIdx.x * BM, c0 = blockIdx.y * BN;
  f32x4 z = {0.f, 0.f, 0.f, 0.f};
  f32x4 acc[2][4];
#pragma unroll
  for (int mi = 0; mi < 2; ++mi)
#pragma unroll
    for (int ni = 0; ni < 4; ++ni) acc[mi][ni] = z;

  for (int k0 = 0; k0 < 256; k0 += BK) {
    stage_A_bf(A, 256, r0, k0, As, t);
    stage_B64(Wt, c0, k0, Bs, t);
    __syncthreads();
    mfma_tile(As, Bs, acc, wave, lane);
    __syncthreads();
  }
  int m16 = lane & 15, quad = lane >> 4;
  float cs[4], cs2[4];
#pragma unroll
  for (int ni = 0; ni < 4; ++ni) { cs[ni] = 0.f; cs2[ni] = 0.f; }
#pragma unroll
  for (int mi = 0; mi < 2; ++mi)
#pragma unroll
    for (int ni = 0; ni < 4; ++ni) {
      int col = c0 + ni * 16 + m16;
      float bv = bias[col];
#pragma unroll
      for (int r = 0; r < 4; ++r) {
        int row = r0 + wave * 32 + mi * 16 + quad * 4 + r;
        float v = acc[mi][ni][r] + bv;
        if constexpr (STATS) { cs[ni] += v; cs2[ni] += v * v; }
        if constexpr (F32OUT)
          ((float*)out)[(size_t)row * LDOUT + col] = v;
        else
          ((unsigned short*)out)[(size_t)row * LDOUT + col] = f2bf(v);
      }
    }
  if constexpr (STATS) {
#pragma unroll
    for (int ni = 0; ni < 4; ++ni) {
      float a = cs[ni], b2 = cs2[ni];
      a += __shfl_xor(a, 16); a += __shfl_xor(a, 32);
      b2 += __shfl_xor(b2, 16); b2 += __shfl_xor(b2, 32);
      if (quad == 0) {
        atomicAdd(&sums[c0 + ni * 16 + m16], a);
        atomicAdd(&sums[256 + c0 + ni * 16 + m16], b2);
      }
    }
  }
}

// ---------------- MFMA flash attention, KT=128 key tiles ----------------
// Block = (graph*8+head, qchunk of 128). 4 waves x 32 q-rows each.
// 3 barriers per 128 keys (stage Vt / S->P done / PV done) vs 8 in round 3.
// No max-subtraction (|s| bounded); padded keys add exactly 1 each -> +(M-c).
__global__ __launch_bounds__(256) void k_attn_mfma(const unsigned short* __restrict__ qkv,
                                                   const int* __restrict__ meta,
                                                   unsigned short* __restrict__ ctx) {
  int b = blockIdx.x >> 3, head = blockIdx.x & 7;
  int c = meta[b], st = meta[NB + b], M = meta[2 * NB];
  int q0 = blockIdx.y * 128;
  if (q0 >= c) return;

  __shared__ unsigned short Vt[32][KT + 8];      // V^T tile [d][key]
  __shared__ unsigned short Pl[4][32][KT + 8];   // per-wave P [qrow][key]

  int t = threadIdx.x, lane = t & 63, wave = t >> 6;
  int m16 = lane & 15, quad = lane >> 4;
  const float SCALE = 0.17677669529663687f;  // 1/sqrt(32)
  float extra = (float)(M - c);

  int qbase = q0 + wave * 32;
  frag8 qf[2];
#pragma unroll
  for (int qg = 0; qg < 2; ++qg) {
    int qrow = qbase + qg * 16 + m16;  // may exceed c: garbage, discarded at store
    qf[qg] = *(const frag8*)(qkv + (size_t)(st + qrow) * 768 + head * 32 + quad * 8);
  }

  f32x4 zz = {0.f, 0.f, 0.f, 0.f};
  f32x4 O[2][2];
  float lp[2][4];
#pragma unroll
  for (int qg = 0; qg < 2; ++qg) {
    O[qg][0] = zz; O[qg][1] = zz;
#pragma unroll
    for (int r = 0; r < 4; ++r) lp[qg][r] = 0.f;
  }

  for (int kt = 0; kt < c; kt += KT) {
    {  // stage V^T tile: 128 keys x 32 d (OOB keys: finite garbage, masked by p=0)
      int key = t >> 1, dh0 = (t & 1) * 16;
      const unsigned short* vp = qkv + (size_t)(st + kt + key) * 768 + 512 + head * 32 + dh0;
      ushort8 v0 = *(const ushort8*)vp;
      ushort8 v1 = *(const ushort8*)(vp + 8);
#pragma unroll
      for (int i = 0; i < 8; ++i) {
        Vt[dh0 + i][key] = v0[i];
        Vt[dh0 + 8 + i][key] = v1[i];
      }
    }
    __syncthreads();

    // S = Q K^T -> p = exp(S*scale) -> per-wave Pl (A-layout transpose via LDS)
#pragma unroll
    for (int sub = 0; sub < 4; ++sub) {
      int ks = kt + sub * 32;
      frag8 kf[2];
#pragma unroll
      for (int hf = 0; hf < 2; ++hf) {
        int krow = ks + hf * 16 + m16;
        kf[hf] = *(const frag8*)(qkv + (size_t)(st + krow) * 768 + 256 + head * 32 + quad * 8);
      }
#pragma unroll
      for (int qg = 0; qg < 2; ++qg)
#pragma unroll
        for (int hf = 0; hf < 2; ++hf) {
          f32x4 s = __builtin_amdgcn_mfma_f32_16x16x32_bf16(qf[qg], kf[hf], zz, 0, 0, 0);
          int key = ks + hf * 16 + m16;
          float msk = (key < c) ? 1.f : 0.f;
#pragma unroll
          for (int r = 0; r < 4; ++r) {
            float p = msk * __expf(s[r] * SCALE);
            lp[qg][r] += p;
            Pl[wave][qg * 16 + quad * 4 + r][sub * 32 + hf * 16 + m16] = f2bf(p);
          }
        }
    }
    __syncthreads();

    // PV over the 128-key tile (4 chunks of K=32)
#pragma unroll
    for (int sub = 0; sub < 4; ++sub) {
      frag8 vf[2];
#pragma unroll
      for (int dh = 0; dh < 2; ++dh)
        vf[dh] = *(const frag8*)&Vt[dh * 16 + m16][sub * 32 + quad * 8];
#pragma unroll
      for (int qg = 0; qg < 2; ++qg) {
        frag8 pf = *(const frag8*)&Pl[wave][qg * 16 + m16][sub * 32 + quad * 8];
#pragma unroll
        for (int dh = 0; dh < 2; ++dh)
          O[qg][dh] = __builtin_amdgcn_mfma_f32_16x16x32_bf16(pf, vf[dh], O[qg][dh], 0, 0, 0);
      }
    }
    __syncthreads();
  }

  // row-sum of lp across the 16 lanes sharing a quad
#pragma unroll
  for (int qg = 0; qg < 2; ++qg)
#pragma unroll
    for (int r = 0; r < 4; ++r) {
      float v = lp[qg][r];
      v += __shfl_xor(v, 1, 16);
      v += __shfl_xor(v, 2, 16);
      v += __shfl_xor(v, 4, 16);
      v += __shfl_xor(v, 8, 16);
      lp[qg][r] = v;
    }

#pragma unroll
  for (int qg = 0; qg < 2; ++qg)
#pragma unroll
    for (int r = 0; r < 4; ++r) {
      int qrow = qbase + qg * 16 + quad * 4 + r;
      if (qrow < c) {
        float inv = 1.f / (lp[qg][r] + extra);
        unsigned short* op = ctx + (size_t)(st + qrow) * 256 + head * 32;
        op[m16] = f2bf(O[qg][0][r] * inv);
        op[16 + m16] = f2bf(O[qg][1][r] * inv);
      }
    }
}

// ---------------- BatchNorm: finalize, apply+ReLU ----------------
__global__ void k_bn_final(const float* __restrict__ sums, const float* __restrict__ gamma,
                           const float* __restrict__ beta, float* __restrict__ bnp) {
  int c = threadIdx.x;
  float mean = sums[c] * (1.0f / NN);
  float var = sums[256 + c] * (1.0f / NN) - mean * mean;  // biased, ddof=0
  float sc = rsqrtf(var + 1e-5f) * gamma[c];
  bnp[c] = sc;
  bnp[256 + c] = beta[c] - mean * sc;
}

__global__ __launch_bounds__(256) void k_bn_apply(const float* __restrict__ h,
                                                  const float* __restrict__ bnp,
                                                  float* __restrict__ out) {
  size_t i4 = (size_t)blockIdx.x * 256 + threadIdx.x;
  float4 v = *(const float4*)(h + i4 * 4);
  int c = (int)((i4 * 4) & 255);
  float4 sc = *(const float4*)(bnp + c);
  float4 sh = *(const float4*)(bnp + 256 + c);
  float4 r;
  r.x = fmaxf(v.x * sc.x + sh.x, 0.f);
  r.y = fmaxf(v.y * sc.y + sh.y, 0.f);
  r.z = fmaxf(v.z * sc.z + sh.z, 0.f);
  r.w = fmaxf(v.w * sc.w + sh.w, 0.f);
  *(float4*)(out + i4 * 4) = r;
}

extern "C" void kernel_launch(void* const* d_in, const int* in_sizes, int n_in,
                              void* d_out, int out_size, void* d_ws, size_t ws_size,
                              hipStream_t stream) {
  const float* x      = (const float*)d_in[0];
  const float* spec   = (const float*)d_in[1];
  const float* Ws     = (const float*)d_in[2];
  const float* bs     = (const float*)d_in[3];
  const float* Win    = (const float*)d_in[4];
  const float* b_in   = (const float*)d_in[5];
  const float* Wout   = (const float*)d_in[6];
  const float* b_out  = (const float*)d_in[7];
  const float* gamma  = (const float*)d_in[8];
  const float* beta   = (const float*)d_in[9];
  const int* batch    = (const int*)d_in[10];   // harness passes integers as int32
  float* out = (float*)d_out;

  char* w = (char*)d_ws;
  size_t off = 0;
  auto alloc = [&](size_t bytes) -> void* {
    off = (off + 255) & ~(size_t)255;
    void* p = w + off; off += bytes; return p;
  };
  int* meta             = (int*)alloc(129 * sizeof(int));
  unsigned short* wst   = (unsigned short*)alloc((size_t)4 * 64 * 256 * 2);
  unsigned short* winb  = (unsigned short*)alloc((size_t)768 * 256 * 2);
  unsigned short* woutb = (unsigned short*)alloc((size_t)256 * 256 * 2);
  float* sums           = (float*)alloc(512 * 4);
  float* bnp            = (float*)alloc(512 * 4);
  unsigned short* h     = (unsigned short*)alloc((size_t)NN * 256 * 2);
  unsigned short* qkv   = (unsigned short*)alloc((size_t)NN * 768 * 2);
  unsigned short* ctx   = (unsigned short*)alloc((size_t)NN * 256 * 2);
  float* hatt           = (float*)alloc((size_t)NN * 256 * 4);

  hipMemsetAsync(sums, 0, 512 * 4, stream);
  k_bounds<<<NN / 256, 256, 0, stream>>>(batch, meta);
  k_meta2<<<1, 64, 0, stream>>>(meta);
  k_prep<<<1280, 256, 0, stream>>>(Ws, Win, Wout, wst, winb, woutb);
  k_scale<<<dim3(NN / BM, 4), 256, 0, stream>>>(x, spec, wst, bs, h);
  k_lin<768, false, false><<<dim3(NN / BM, 12), 256, 0, stream>>>(h, winb, b_in, qkv, nullptr);
  k_attn_mfma<<<dim3(NB * NHEAD, 8), 256, 0, stream>>>(qkv, meta, ctx);
  k_lin<256, true, true><<<dim3(NN / BM, 4), 256, 0, stream>>>(ctx, woutb, b_out, hatt, sums);
  k_bn_final<<<1, 256, 0, stream>>>(sums, gamma, beta, bnp);
  k_bn_apply<<<NN * 256 / 1024, 256, 0, stream>>>(hatt, bnp, out);
}

// Round 5
// 440.668 us; speedup vs baseline: 2.7740x; 1.0324x over previous
//
#include <hip/hip_runtime.h>

// SpectralConvLayer: per-scale linear (x+spectral)@Ws concat -> ragged MHA
// (no key-padding mask: padded keys contribute exp(0)=1 to denom) -> out-proj
// -> BatchNorm(batch stats) -> ReLU.
// Round 5: attn computes S^T = K*Q^T so the P transpose to A-layout is done with
// shuffles (no P LDS, no S->PV barrier; LDS = Vt only -> occupancy). k_lin BN=128.

typedef __attribute__((ext_vector_type(8))) short frag8;      // 8 bf16 (4 VGPR)
typedef __attribute__((ext_vector_type(4))) float f32x4;
typedef __attribute__((ext_vector_type(8))) unsigned short ushort8;

#define NN 32768
#define NB 64
#define CIN 256
#define COUT 256
#define NHEAD 8
#define HD 32

#define BM 128
#define BK 64
#define LDK 72   // +8 shorts pad: breaks pow2 LDS strides
#define KT 128   // attention key-tile (V staging)

__device__ inline unsigned short f2bf(float f) {
  unsigned u = __builtin_bit_cast(unsigned, f);
  u += 0x7FFFu + ((u >> 16) & 1u);          // RNE
  return (unsigned short)(u >> 16);
}
__device__ inline unsigned pack2bf(float a, float b) {
  return (unsigned)f2bf(a) | ((unsigned)f2bf(b) << 16);
}

// ---------------- meta: batch sorted -> starts via boundaries ----------------
__global__ void k_bounds(const int* __restrict__ batch, int* __restrict__ meta) {
  int i = blockIdx.x * 256 + threadIdx.x;
  if (i >= NN) return;
  int v = batch[i];
  int prev = (i == 0) ? -1 : batch[i - 1];
  for (int bb = prev + 1; bb <= v; ++bb) meta[NB + bb] = i;  // starts
}
__global__ void k_meta2(int* __restrict__ meta) {
  __shared__ int mx[NB];
  int b = threadIdx.x;  // 64 threads
  int s = meta[NB + b];
  int e = (b == 63) ? NN : meta[NB + b + 1];
  meta[b] = e - s;
  mx[b] = e - s;
  __syncthreads();
  if (b == 0) {
    int m = 0;
    for (int j = 0; j < NB; ++j) m = max(m, mx[j]);
    meta[2 * NB] = m;
  }
}

// ---------------- weight prep: fp32 -> bf16, B laid out as Bt[n][k] ----------------
__global__ void k_prep(const float* __restrict__ Ws, const float* __restrict__ Win,
                       const float* __restrict__ Wout,
                       unsigned short* __restrict__ wst, unsigned short* __restrict__ winb,
                       unsigned short* __restrict__ woutb) {
  int tid = blockIdx.x * 256 + threadIdx.x;
  if (tid < 4 * 64 * 256) {
    int s = tid >> 14, rem = tid & 16383, o = rem >> 8, i = rem & 255;
    wst[tid] = f2bf(Ws[((s * 256) + i) * 64 + o]);
  } else if (tid < 4 * 64 * 256 + 768 * 256) {
    int t2 = tid - 4 * 64 * 256;
    winb[t2] = f2bf(Win[t2]);
  } else if (tid < 4 * 64 * 256 + 768 * 256 + 256 * 256) {
    int t3 = tid - (4 * 64 * 256 + 768 * 256);
    woutb[t3] = f2bf(Wout[t3]);
  }
}

// ---------------- shared GEMM pieces ----------------
// A-frag: lane(m=l&15,q=l>>4) holds A[m][q*8+j]
// B-frag: lane(n=l&15,q)      holds B[q*8+j][n] = Bt[n][q*8+j]
// C/D   : lane holds D[q*4+reg][l&15]            (measured m89/m91)
template <int NT>
__device__ inline void mfma_tile(const unsigned short (*As)[LDK],
                                 const unsigned short (*Bs)[LDK],
                                 f32x4 acc[2][NT], int wave, int lane) {
  int m16 = lane & 15, quad = lane >> 4;
#pragma unroll
  for (int kk = 0; kk < 2; ++kk) {
    frag8 a[2], b[NT];
#pragma unroll
    for (int mi = 0; mi < 2; ++mi)
      a[mi] = *(const frag8*)&As[wave * 32 + mi * 16 + m16][kk * 32 + quad * 8];
#pragma unroll
    for (int ni = 0; ni < NT; ++ni)
      b[ni] = *(const frag8*)&Bs[ni * 16 + m16][kk * 32 + quad * 8];
#pragma unroll
    for (int mi = 0; mi < 2; ++mi)
#pragma unroll
      for (int ni = 0; ni < NT; ++ni)
        acc[mi][ni] = __builtin_amdgcn_mfma_f32_16x16x32_bf16(a[mi], b[ni], acc[mi][ni], 0, 0, 0);
  }
}

__device__ inline void stage_B64(const unsigned short* __restrict__ Wt, int c0, int k0,
                                 unsigned short (*Bs)[LDK], int t) {
  int n = t & 63, seg = t >> 6;
  const unsigned short* src = Wt + (size_t)(c0 + n) * 256 + k0 + seg * 16;
  uint4 v0 = *(const uint4*)src;
  uint4 v1 = *(const uint4*)(src + 8);
  *(uint4*)&Bs[n][seg * 16] = v0;
  *(uint4*)&Bs[n][seg * 16 + 8] = v1;
}

__device__ inline void stage_B128(const unsigned short* __restrict__ Wt, int c0, int k0,
                                  unsigned short (*Bs)[LDK], int t) {
  int n = t >> 1, half = t & 1;
  const unsigned short* src = Wt + (size_t)(c0 + n) * 256 + k0 + half * 32;
#pragma unroll
  for (int i = 0; i < 4; ++i) {
    uint4 v = *(const uint4*)(src + i * 8);
    *(uint4*)&Bs[n][half * 32 + i * 8] = v;
  }
}

__device__ inline void stage_A_bf(const unsigned short* __restrict__ A, int lda, int r0, int k0,
                                  unsigned short (*As)[LDK], int t) {
  int r = t >> 1, half = t & 1;
  const unsigned short* src = A + (size_t)(r0 + r) * lda + k0 + half * 32;
#pragma unroll
  for (int i = 0; i < 4; ++i) {
    uint4 v = *(const uint4*)(src + i * 8);
    *(uint4*)&As[r][half * 32 + i * 8] = v;
  }
}

// ---------------- scale-linear: h[n, s*64+o] = (x+spec_s)[n,:] @ Ws[s] + bs ----------------
__global__ __launch_bounds__(256) void k_scale(const float* __restrict__ x,
                                               const float* __restrict__ spec,
                                               const unsigned short* __restrict__ wst,
                                               const float* __restrict__ bs,
                                               unsigned short* __restrict__ h) {
  __shared__ unsigned short As[BM][LDK];
  __shared__ unsigned short Bs[64][LDK];
  int t = threadIdx.x, lane = t & 63, wave = t >> 6;
  int r0 = blockIdx.x * BM, s = blockIdx.y;
  f32x4 z = {0.f, 0.f, 0.f, 0.f};
  f32x4 acc[2][4];
#pragma unroll
  for (int mi = 0; mi < 2; ++mi)
#pragma unroll
    for (int ni = 0; ni < 4; ++ni) acc[mi][ni] = z;

  const float* sb = spec + (size_t)s * NN * CIN;
  for (int k0 = 0; k0 < CIN; k0 += BK) {
    {  // fused A staging: fp32 x + spectral -> bf16 LDS
      int r = t >> 1, half = t & 1;
      const float* xs = x + (size_t)(r0 + r) * CIN + k0 + half * 32;
      const float* ss = sb + (size_t)(r0 + r) * CIN + k0 + half * 32;
#pragma unroll
      for (int i = 0; i < 8; ++i) {
        float4 xv = *(const float4*)(xs + i * 4);
        float4 sv = *(const float4*)(ss + i * 4);
        ushort4 o;
        o.x = f2bf(xv.x + sv.x); o.y = f2bf(xv.y + sv.y);
        o.z = f2bf(xv.z + sv.z); o.w = f2bf(xv.w + sv.w);
        *(ushort4*)&As[r][half * 32 + i * 4] = o;
      }
    }
    stage_B64(wst + (size_t)s * 64 * 256, 0, k0, Bs, t);
    __syncthreads();
    mfma_tile<4>(As, Bs, acc, wave, lane);
    __syncthreads();
  }
  int m16 = lane & 15, quad = lane >> 4;
#pragma unroll
  for (int mi = 0; mi < 2; ++mi)
#pragma unroll
    for (int ni = 0; ni < 4; ++ni) {
      int col = ni * 16 + m16;
      float bias = bs[s * 64 + col];
#pragma unroll
      for (int r = 0; r < 4; ++r) {
        int row = r0 + wave * 32 + mi * 16 + quad * 4 + r;
        h[(size_t)row * COUT + s * 64 + col] = f2bf(acc[mi][ni][r] + bias);
      }
    }
}

// ------- bf16 GEMM, BN=128; STATS fuses BatchNorm sum/sumsq reduction -------
template <int LDOUT, bool F32OUT, bool STATS>
__global__ __launch_bounds__(256) void k_lin(const unsigned short* __restrict__ A,
                                             const unsigned short* __restrict__ Wt,
                                             const float* __restrict__ bias,
                                             void* __restrict__ out,
                                             float* __restrict__ sums) {
  __shared__ unsigned short As[BM][LDK];
  __shared__ unsigned short Bs[128][LDK];
  int t = threadIdx.x, lane = t & 63, wave = t >> 6;
  int r0 = blockIdx.x * BM, c0 = blockIdx.y * 128;
  f32x4 z = {0.f, 0.f, 0.f, 0.f};
  f32x4 acc[2][8];
#pragma unroll
  for (int mi = 0; mi < 2; ++mi)
#pragma unroll
    for (int ni = 0; ni < 8; ++ni) acc[mi][ni] = z;

  for (int k0 = 0; k0 < 256; k0 += BK) {
    stage_A_bf(A, 256, r0, k0, As, t);
    stage_B128(Wt, c0, k0, Bs, t);
    __syncthreads();
    mfma_tile<8>(As, Bs, acc, wave, lane);
    __syncthreads();
  }
  int m16 = lane & 15, quad = lane >> 4;
  float cs[8], cs2[8];
#pragma unroll
  for (int ni = 0; ni < 8; ++ni) { cs[ni] = 0.f; cs2[ni] = 0.f; }
#pragma unroll
  for (int mi = 0; mi < 2; ++mi)
#pragma unroll
    for (int ni = 0; ni < 8; ++ni) {
      int col = c0 + ni * 16 + m16;
      float bv = bias[col];
#pragma unroll
      for (int r = 0; r < 4; ++r) {
        int row = r0 + wave * 32 + mi * 16 + quad * 4 + r;
        float v = acc[mi][ni][r] + bv;
        if constexpr (STATS) { cs[ni] += v; cs2[ni] += v * v; }
        if constexpr (F32OUT)
          ((float*)out)[(size_t)row * LDOUT + col] = v;
        else
          ((unsigned short*)out)[(size_t)row * LDOUT + col] = f2bf(v);
      }
    }
  if constexpr (STATS) {
#pragma unroll
    for (int ni = 0; ni < 8; ++ni) {
      float a = cs[ni], b2 = cs2[ni];
      a += __shfl_xor(a, 16); a += __shfl_xor(a, 32);
      b2 += __shfl_xor(b2, 16); b2 += __shfl_xor(b2, 32);
      if (quad == 0) {
        atomicAdd(&sums[c0 + ni * 16 + m16], a);
        atomicAdd(&sums[256 + c0 + ni * 16 + m16], b2);
      }
    }
  }
}

// ---------------- MFMA flash attention, S^T + shuffle transpose ----------------
// Block = (graph*8+head, qchunk of 128). 4 waves x 32 q-rows each.
// S^T = K*Q^T: same global fragments as S=Q*K^T with operands swapped; the P
// values then sit key-major in the C-layout, so the PV A-fragment is built with
// shuffles — no P LDS, no S->PV barrier. LDS holds only Vt (2 barriers/128 keys).
// No max-subtraction (|s| bounded); padded keys add exactly 1 each -> +(M-c).
__global__ __launch_bounds__(256) void k_attn_mfma(const unsigned short* __restrict__ qkv,
                                                   const int* __restrict__ meta,
                                                   unsigned short* __restrict__ ctx) {
  int b = blockIdx.x >> 3, head = blockIdx.x & 7;
  int c = meta[b], st = meta[NB + b], M = meta[2 * NB];
  int q0 = blockIdx.y * 128;
  if (q0 >= c) return;

  __shared__ unsigned short Vt[32][KT + 8];   // V^T tile [d][key]

  int t = threadIdx.x, lane = t & 63, wave = t >> 6;
  int m16 = lane & 15, quad = lane >> 4;
  const float SCALE = 0.17677669529663687f;   // 1/sqrt(32)
  float extra = (float)(M - c);

  int qbase = q0 + wave * 32;
  frag8 qf[2];
#pragma unroll
  for (int qg = 0; qg < 2; ++qg) {
    int qrow = qbase + qg * 16 + m16;  // may exceed c: garbage, discarded at store
    qf[qg] = *(const frag8*)(qkv + (size_t)(st + qrow) * 768 + head * 32 + quad * 8);
  }

  f32x4 zz = {0.f, 0.f, 0.f, 0.f};
  f32x4 O[2][2];
  float lp[2] = {0.f, 0.f};
#pragma unroll
  for (int qg = 0; qg < 2; ++qg) { O[qg][0] = zz; O[qg][1] = zz; }

  int sl0 = m16 + ((quad & 1) << 5);   // shuffle sources for the P transpose
  int sl1 = sl0 + 16;

  for (int kt = 0; kt < c; kt += KT) {
    {  // stage V^T tile: 128 keys x 32 d (OOB keys: finite garbage, masked by p=0)
      int key = t >> 1, dh0 = (t & 1) * 16;
      const unsigned short* vp = qkv + (size_t)(st + kt + key) * 768 + 512 + head * 32 + dh0;
      ushort8 v0 = *(const ushort8*)vp;
      ushort8 v1 = *(const ushort8*)(vp + 8);
#pragma unroll
      for (int i = 0; i < 8; ++i) {
        Vt[dh0 + i][key] = v0[i];
        Vt[dh0 + 8 + i][key] = v1[i];
      }
    }
    __syncthreads();

#pragma unroll
    for (int sub = 0; sub < 4; ++sub) {
      int ks = kt + sub * 32;
      // K fragments as the A operand (rows = keys)
      frag8 kf[2];
#pragma unroll
      for (int kh = 0; kh < 2; ++kh) {
        int krow = ks + kh * 16 + m16;
        kf[kh] = *(const frag8*)(qkv + (size_t)(st + krow) * 768 + 256 + head * 32 + quad * 8);
      }
      // S^T tiles: D[key=quad*4+r][q=m16]; p packed 2xbf16 per dword
      unsigned pk[2][2][2];  // [qg][khalf][dword]
#pragma unroll
      for (int qg = 0; qg < 2; ++qg)
#pragma unroll
        for (int kh = 0; kh < 2; ++kh) {
          f32x4 s = __builtin_amdgcn_mfma_f32_16x16x32_bf16(kf[kh], qf[qg], zz, 0, 0, 0);
          float p[4];
#pragma unroll
          for (int r = 0; r < 4; ++r) {
            int key = ks + kh * 16 + quad * 4 + r;
            float msk = (key < c) ? 1.f : 0.f;
            p[r] = msk * __expf(s[r] * SCALE);
            lp[qg] += p[r];
          }
          pk[qg][kh][0] = pack2bf(p[0], p[1]);
          pk[qg][kh][1] = pack2bf(p[2], p[3]);
        }
      // V fragments from Vt
      frag8 vf[2];
#pragma unroll
      for (int dh = 0; dh < 2; ++dh)
        vf[dh] = *(const frag8*)&Vt[dh * 16 + m16][sub * 32 + quad * 8];
      // Build P A-fragments by shuffle and run PV
#pragma unroll
      for (int qg = 0; qg < 2; ++qg) {
        unsigned a0 = __shfl(pk[qg][0][0], sl0), a1 = __shfl(pk[qg][0][1], sl0);
        unsigned a2 = __shfl(pk[qg][0][0], sl1), a3 = __shfl(pk[qg][0][1], sl1);
        unsigned b0 = __shfl(pk[qg][1][0], sl0), b1 = __shfl(pk[qg][1][1], sl0);
        unsigned b2 = __shfl(pk[qg][1][0], sl1), b3 = __shfl(pk[qg][1][1], sl1);
        uint4 pw;
        pw.x = (quad < 2) ? a0 : b0;
        pw.y = (quad < 2) ? a1 : b1;
        pw.z = (quad < 2) ? a2 : b2;
        pw.w = (quad < 2) ? a3 : b3;
        frag8 pf = __builtin_bit_cast(frag8, pw);
#pragma unroll
        for (int dh = 0; dh < 2; ++dh)
          O[qg][dh] = __builtin_amdgcn_mfma_f32_16x16x32_bf16(pf, vf[dh], O[qg][dh], 0, 0, 0);
      }
    }
    __syncthreads();
  }

  // lp currently per-lane partial (q = m16); reduce over quads
#pragma unroll
  for (int qg = 0; qg < 2; ++qg) {
    float v = lp[qg];
    v += __shfl_xor(v, 16);
    v += __shfl_xor(v, 32);
    lp[qg] = v;
  }

#pragma unroll
  for (int qg = 0; qg < 2; ++qg)
#pragma unroll
    for (int r = 0; r < 4; ++r) {
      int qrow = qbase + qg * 16 + quad * 4 + r;
      float lsum = __shfl(lp[qg], quad * 4 + r);  // l for this O-row
      if (qrow < c) {
        float inv = 1.f / (lsum + extra);
        unsigned short* op = ctx + (size_t)(st + qrow) * 256 + head * 32;
        op[m16] = f2bf(O[qg][0][r] * inv);
        op[16 + m16] = f2bf(O[qg][1][r] * inv);
      }
    }
}

// ---------------- BatchNorm: finalize, apply+ReLU ----------------
__global__ void k_bn_final(const float* __restrict__ sums, const float* __restrict__ gamma,
                           const float* __restrict__ beta, float* __restrict__ bnp) {
  int c = threadIdx.x;
  float mean = sums[c] * (1.0f / NN);
  float var = sums[256 + c] * (1.0f / NN) - mean * mean;  // biased, ddof=0
  float sc = rsqrtf(var + 1e-5f) * gamma[c];
  bnp[c] = sc;
  bnp[256 + c] = beta[c] - mean * sc;
}

__global__ __launch_bounds__(256) void k_bn_apply(const float* __restrict__ h,
                                                  const float* __restrict__ bnp,
                                                  float* __restrict__ out) {
  size_t i4 = (size_t)blockIdx.x * 256 + threadIdx.x;
  float4 v = *(const float4*)(h + i4 * 4);
  int c = (int)((i4 * 4) & 255);
  float4 sc = *(const float4*)(bnp + c);
  float4 sh = *(const float4*)(bnp + 256 + c);
  float4 r;
  r.x = fmaxf(v.x * sc.x + sh.x, 0.f);
  r.y = fmaxf(v.y * sc.y + sh.y, 0.f);
  r.z = fmaxf(v.z * sc.z + sh.z, 0.f);
  r.w = fmaxf(v.w * sc.w + sh.w, 0.f);
  *(float4*)(out + i4 * 4) = r;
}

extern "C" void kernel_launch(void* const* d_in, const int* in_sizes, int n_in,
                              void* d_out, int out_size, void* d_ws, size_t ws_size,
                              hipStream_t stream) {
  const float* x      = (const float*)d_in[0];
  const float* spec   = (const float*)d_in[1];
  const float* Ws     = (const float*)d_in[2];
  const float* bs     = (const float*)d_in[3];
  const float* Win    = (const float*)d_in[4];
  const float* b_in   = (const float*)d_in[5];
  const float* Wout   = (const float*)d_in[6];
  const float* b_out  = (const float*)d_in[7];
  const float* gamma  = (const float*)d_in[8];
  const float* beta   = (const float*)d_in[9];
  const int* batch    = (const int*)d_in[10];   // harness passes integers as int32
  float* out = (float*)d_out;

  char* w = (char*)d_ws;
  size_t off = 0;
  auto alloc = [&](size_t bytes) -> void* {
    off = (off + 255) & ~(size_t)255;
    void* p = w + off; off += bytes; return p;
  };
  int* meta             = (int*)alloc(129 * sizeof(int));
  unsigned short* wst   = (unsigned short*)alloc((size_t)4 * 64 * 256 * 2);
  unsigned short* winb  = (unsigned short*)alloc((size_t)768 * 256 * 2);
  unsigned short* woutb = (unsigned short*)alloc((size_t)256 * 256 * 2);
  float* sums           = (float*)alloc(512 * 4);
  float* bnp            = (float*)alloc(512 * 4);
  unsigned short* h     = (unsigned short*)alloc((size_t)NN * 256 * 2);
  unsigned short* qkv   = (unsigned short*)alloc((size_t)NN * 768 * 2);
  unsigned short* ctx   = (unsigned short*)alloc((size_t)NN * 256 * 2);
  float* hatt           = (float*)alloc((size_t)NN * 256 * 4);

  hipMemsetAsync(sums, 0, 512 * 4, stream);
  k_bounds<<<NN / 256, 256, 0, stream>>>(batch, meta);
  k_meta2<<<1, 64, 0, stream>>>(meta);
  k_prep<<<1280, 256, 0, stream>>>(Ws, Win, Wout, wst, winb, woutb);
  k_scale<<<dim3(NN / BM, 4), 256, 0, stream>>>(x, spec, wst, bs, h);
  k_lin<768, false, false><<<dim3(NN / BM, 6), 256, 0, stream>>>(h, winb, b_in, qkv, nullptr);
  k_attn_mfma<<<dim3(NB * NHEAD, 8), 256, 0, stream>>>(qkv, meta, ctx);
  k_lin<256, true, true><<<dim3(NN / BM, 2), 256, 0, stream>>>(ctx, woutb, b_out, hatt, sums);
  k_bn_final<<<1, 256, 0, stream>>>(sums, gamma, beta, bnp);
  k_bn_apply<<<NN * 256 / 1024, 256, 0, stream>>>(hatt, bnp, out);
}

// Round 7
// 416.202 us; speedup vs baseline: 2.9371x; 1.0588x over previous
//
#include <hip/hip_runtime.h>

// SpectralConvLayer: per-scale linear (x+spectral)@Ws concat -> ragged MHA
// (no key-padding mask: padded keys contribute exp(0)=1 to denom) -> out-proj
// -> BatchNorm(batch stats) -> ReLU.
// Round 7: same as round 6 (PV via 16x16x16 MFMA: S^T C-layout == its A-frag
// layout, no shuffles; mask-free main chunks; hatt bf16; fused bn/bounds) with
// the pack2bf compile fix (manual RNE pack, no __hip_bfloat162 bit_cast).

typedef __attribute__((ext_vector_type(8))) short frag8;      // 8 bf16 (4 VGPR)
typedef __attribute__((ext_vector_type(4))) short frag4;      // 4 bf16 (2 VGPR)
typedef __attribute__((ext_vector_type(4))) float f32x4;
typedef __attribute__((ext_vector_type(8))) unsigned short ushort8;
typedef __attribute__((ext_vector_type(2))) unsigned int uint2e;

#define NN 32768
#define NB 64
#define CIN 256
#define COUT 256
#define NHEAD 8
#define HD 32

#define BM 128
#define BK 64
#define LDK 72   // +8 shorts pad: breaks pow2 LDS strides
#define KT 128   // attention key-tile (V staging)

#if __has_builtin(__builtin_amdgcn_mfma_f32_16x16x16bf16_1k)
#define HAS_MFMA16 1
#else
#define HAS_MFMA16 0
#endif

__device__ inline unsigned short f2bf(float f) {
  unsigned u = __builtin_bit_cast(unsigned, f);
  u += 0x7FFFu + ((u >> 16) & 1u);          // RNE
  return (unsigned short)(u >> 16);
}
__device__ inline float bf2f(unsigned short h) {
  return __builtin_bit_cast(float, (unsigned)h << 16);
}
__device__ inline unsigned pack2bf(float a, float b) {
  return (unsigned)f2bf(a) | ((unsigned)f2bf(b) << 16);
}

// ---------------- prep (fp32->bf16 weights, Ws transposed) + batch boundaries ----
__global__ void k_prep(const float* __restrict__ Ws, const float* __restrict__ Win,
                       const float* __restrict__ Wout, const int* __restrict__ batch,
                       unsigned short* __restrict__ wst, unsigned short* __restrict__ winb,
                       unsigned short* __restrict__ woutb, int* __restrict__ meta) {
  int tid = blockIdx.x * 256 + threadIdx.x;
  if (tid < NN) {  // boundary detection on sorted batch -> starts
    int v = batch[tid];
    int prev = (tid == 0) ? -1 : batch[tid - 1];
    for (int bb = prev + 1; bb <= v; ++bb) meta[NB + bb] = tid;
  }
  if (tid < 4 * 64 * 256) {
    int s = tid >> 14, rem = tid & 16383, o = rem >> 8, i = rem & 255;
    wst[tid] = f2bf(Ws[((s * 256) + i) * 64 + o]);
  } else if (tid < 4 * 64 * 256 + 768 * 256) {
    int t2 = tid - 4 * 64 * 256;
    winb[t2] = f2bf(Win[t2]);
  } else if (tid < 4 * 64 * 256 + 768 * 256 + 256 * 256) {
    int t3 = tid - (4 * 64 * 256 + 768 * 256);
    woutb[t3] = f2bf(Wout[t3]);
  }
}
__global__ void k_meta2(int* __restrict__ meta) {
  __shared__ int mx[NB];
  int b = threadIdx.x;  // 64 threads
  int s = meta[NB + b];
  int e = (b == 63) ? NN : meta[NB + b + 1];
  meta[b] = e - s;
  mx[b] = e - s;
  __syncthreads();
  if (b == 0) {
    int m = 0;
    for (int j = 0; j < NB; ++j) m = max(m, mx[j]);
    meta[2 * NB] = m;
  }
}

// ---------------- shared GEMM pieces ----------------
// A-frag(16x16x32): lane(m=l&15,q=l>>4) holds A[m][q*8+j]
// B-frag          : lane(n=l&15,q)      holds B[q*8+j][n] = Bt[n][q*8+j]
// C/D             : lane holds D[q*4+reg][l&15]     (measured m89/m91)
template <int NT>
__device__ inline void mfma_tile(const unsigned short (*As)[LDK],
                                 const unsigned short (*Bs)[LDK],
                                 f32x4 acc[2][NT], int wave, int lane) {
  int m16 = lane & 15, quad = lane >> 4;
#pragma unroll
  for (int kk = 0; kk < 2; ++kk) {
    frag8 a[2], b[NT];
#pragma unroll
    for (int mi = 0; mi < 2; ++mi)
      a[mi] = *(const frag8*)&As[wave * 32 + mi * 16 + m16][kk * 32 + quad * 8];
#pragma unroll
    for (int ni = 0; ni < NT; ++ni)
      b[ni] = *(const frag8*)&Bs[ni * 16 + m16][kk * 32 + quad * 8];
#pragma unroll
    for (int mi = 0; mi < 2; ++mi)
#pragma unroll
      for (int ni = 0; ni < NT; ++ni)
        acc[mi][ni] = __builtin_amdgcn_mfma_f32_16x16x32_bf16(a[mi], b[ni], acc[mi][ni], 0, 0, 0);
  }
}

__device__ inline void stage_B64(const unsigned short* __restrict__ Wt, int c0, int k0,
                                 unsigned short (*Bs)[LDK], int t) {
  int n = t & 63, seg = t >> 6;
  const unsigned short* src = Wt + (size_t)(c0 + n) * 256 + k0 + seg * 16;
  uint4 v0 = *(const uint4*)src;
  uint4 v1 = *(const uint4*)(src + 8);
  *(uint4*)&Bs[n][seg * 16] = v0;
  *(uint4*)&Bs[n][seg * 16 + 8] = v1;
}

__device__ inline void stage_B128(const unsigned short* __restrict__ Wt, int c0, int k0,
                                  unsigned short (*Bs)[LDK], int t) {
  int n = t >> 1, half = t & 1;
  const unsigned short* src = Wt + (size_t)(c0 + n) * 256 + k0 + half * 32;
#pragma unroll
  for (int i = 0; i < 4; ++i) {
    uint4 v = *(const uint4*)(src + i * 8);
    *(uint4*)&Bs[n][half * 32 + i * 8] = v;
  }
}

__device__ inline void stage_A_bf(const unsigned short* __restrict__ A, int lda, int r0, int k0,
                                  unsigned short (*As)[LDK], int t) {
  int r = t >> 1, half = t & 1;
  const unsigned short* src = A + (size_t)(r0 + r) * lda + k0 + half * 32;
#pragma unroll
  for (int i = 0; i < 4; ++i) {
    uint4 v = *(const uint4*)(src + i * 8);
    *(uint4*)&As[r][half * 32 + i * 8] = v;
  }
}

// ---------------- scale-linear: h[n, s*64+o] = (x+spec_s)[n,:] @ Ws[s] + bs ----------------
__global__ __launch_bounds__(256) void k_scale(const float* __restrict__ x,
                                               const float* __restrict__ spec,
                                               const unsigned short* __restrict__ wst,
                                               const float* __restrict__ bs,
                                               unsigned short* __restrict__ h) {
  __shared__ unsigned short As[BM][LDK];
  __shared__ unsigned short Bs[64][LDK];
  int t = threadIdx.x, lane = t & 63, wave = t >> 6;
  int r0 = blockIdx.x * BM, s = blockIdx.y;
  f32x4 z = {0.f, 0.f, 0.f, 0.f};
  f32x4 acc[2][4];
#pragma unroll
  for (int mi = 0; mi < 2; ++mi)
#pragma unroll
    for (int ni = 0; ni < 4; ++ni) acc[mi][ni] = z;

  const float* sb = spec + (size_t)s * NN * CIN;
  for (int k0 = 0; k0 < CIN; k0 += BK) {
    {  // fused A staging: fp32 x + spectral -> bf16 LDS
      int r = t >> 1, half = t & 1;
      const float* xs = x + (size_t)(r0 + r) * CIN + k0 + half * 32;
      const float* ss = sb + (size_t)(r0 + r) * CIN + k0 + half * 32;
#pragma unroll
      for (int i = 0; i < 8; ++i) {
        float4 xv = *(const float4*)(xs + i * 4);
        float4 sv = *(const float4*)(ss + i * 4);
        ushort4 o;
        o.x = f2bf(xv.x + sv.x); o.y = f2bf(xv.y + sv.y);
        o.z = f2bf(xv.z + sv.z); o.w = f2bf(xv.w + sv.w);
        *(ushort4*)&As[r][half * 32 + i * 4] = o;
      }
    }
    stage_B64(wst + (size_t)s * 64 * 256, 0, k0, Bs, t);
    __syncthreads();
    mfma_tile<4>(As, Bs, acc, wave, lane);
    __syncthreads();
  }
  int m16 = lane & 15, quad = lane >> 4;
#pragma unroll
  for (int mi = 0; mi < 2; ++mi)
#pragma unroll
    for (int ni = 0; ni < 4; ++ni) {
      int col = ni * 16 + m16;
      float bias = bs[s * 64 + col];
#pragma unroll
      for (int r = 0; r < 4; ++r) {
        int row = r0 + wave * 32 + mi * 16 + quad * 4 + r;
        h[(size_t)row * COUT + s * 64 + col] = f2bf(acc[mi][ni][r] + bias);
      }
    }
}

// ------- bf16 GEMM, BN=128; STATS fuses BatchNorm sum/sumsq reduction -------
template <int LDOUT, bool F32OUT, bool STATS>
__global__ __launch_bounds__(256) void k_lin(const unsigned short* __restrict__ A,
                                             const unsigned short* __restrict__ Wt,
                                             const float* __restrict__ bias,
                                             void* __restrict__ out,
                                             float* __restrict__ sums) {
  __shared__ unsigned short As[BM][LDK];
  __shared__ unsigned short Bs[128][LDK];
  int t = threadIdx.x, lane = t & 63, wave = t >> 6;
  int r0 = blockIdx.x * BM, c0 = blockIdx.y * 128;
  f32x4 z = {0.f, 0.f, 0.f, 0.f};
  f32x4 acc[2][8];
#pragma unroll
  for (int mi = 0; mi < 2; ++mi)
#pragma unroll
    for (int ni = 0; ni < 8; ++ni) acc[mi][ni] = z;

  for (int k0 = 0; k0 < 256; k0 += BK) {
    stage_A_bf(A, 256, r0, k0, As, t);
    stage_B128(Wt, c0, k0, Bs, t);
    __syncthreads();
    mfma_tile<8>(As, Bs, acc, wave, lane);
    __syncthreads();
  }
  int m16 = lane & 15, quad = lane >> 4;
  float cs[8], cs2[8];
#pragma unroll
  for (int ni = 0; ni < 8; ++ni) { cs[ni] = 0.f; cs2[ni] = 0.f; }
#pragma unroll
  for (int mi = 0; mi < 2; ++mi)
#pragma unroll
    for (int ni = 0; ni < 8; ++ni) {
      int col = c0 + ni * 16 + m16;
      float bv = bias[col];
#pragma unroll
      for (int r = 0; r < 4; ++r) {
        int row = r0 + wave * 32 + mi * 16 + quad * 4 + r;
        float v = acc[mi][ni][r] + bv;
        if constexpr (STATS) { cs[ni] += v; cs2[ni] += v * v; }
        if constexpr (F32OUT)
          ((float*)out)[(size_t)row * LDOUT + col] = v;
        else
          ((unsigned short*)out)[(size_t)row * LDOUT + col] = f2bf(v);
      }
    }
  if constexpr (STATS) {
#pragma unroll
    for (int ni = 0; ni < 8; ++ni) {
      float a = cs[ni], b2 = cs2[ni];
      a += __shfl_xor(a, 16); a += __shfl_xor(a, 32);
      b2 += __shfl_xor(b2, 16); b2 += __shfl_xor(b2, 32);
      if (quad == 0) {
        atomicAdd(&sums[c0 + ni * 16 + m16], a);
        atomicAdd(&sums[256 + c0 + ni * 16 + m16], b2);
      }
    }
  }
}

// ---------------- MFMA flash attention ----------------
// Block = (graph*8+head, qchunk of 128). 4 waves x 32 q-rows each.
// S^T = K*Q^T (swapped operands, same global fragments). Its C-layout
// (lane: q=m16, key=quad*4+r) IS the 16x16x16 A-fragment layout, so PV runs as
// 16x16x16 MFMAs with zero cross-lane data movement. Main chunks mask-free;
// only the final partial 32-chunk masks. Padded keys add exactly 1 -> +(M-c).
__global__ __launch_bounds__(256) void k_attn_mfma(const unsigned short* __restrict__ qkv,
                                                   const int* __restrict__ meta,
                                                   unsigned short* __restrict__ ctx) {
  int b = blockIdx.x >> 3, head = blockIdx.x & 7;
  int c = meta[b], st = meta[NB + b], M = meta[2 * NB];
  int q0 = blockIdx.y * 128;
  if (q0 >= c) return;

  __shared__ unsigned short Vt[32][KT + 8];   // V^T tile [d][key]

  int t = threadIdx.x, lane = t & 63, wave = t >> 6;
  int m16 = lane & 15, quad = lane >> 4;
  const float SCALE = 0.17677669529663687f;   // 1/sqrt(32)
  float extra = (float)(M - c);

  int qbase = q0 + wave * 32;
  frag8 qf[2];
#pragma unroll
  for (int qg = 0; qg < 2; ++qg) {
    int qrow = qbase + qg * 16 + m16;  // may exceed c: garbage, discarded at store
    qf[qg] = *(const frag8*)(qkv + (size_t)(st + qrow) * 768 + head * 32 + quad * 8);
  }

  f32x4 zz = {0.f, 0.f, 0.f, 0.f};
  f32x4 O[2][2];
  float lp[2] = {0.f, 0.f};
#pragma unroll
  for (int qg = 0; qg < 2; ++qg) { O[qg][0] = zz; O[qg][1] = zz; }

#if !HAS_MFMA16
  int sl0 = m16 + ((quad & 1) << 5);
  int sl1 = sl0 + 16;
#endif

  for (int kt = 0; kt < c; kt += KT) {
    {  // stage V^T tile: 128 keys x 32 d (OOB keys finite garbage, masked by p=0)
      int key = t >> 1, dh0 = (t & 1) * 16;
      const unsigned short* vp = qkv + (size_t)(st + kt + key) * 768 + 512 + head * 32 + dh0;
      ushort8 v0 = *(const ushort8*)vp;
      ushort8 v1 = *(const ushort8*)(vp + 8);
#pragma unroll
      for (int i = 0; i < 8; ++i) {
        Vt[dh0 + i][key] = v0[i];
        Vt[dh0 + 8 + i][key] = v1[i];
      }
    }
    __syncthreads();

#pragma unroll
    for (int sub = 0; sub < 4; ++sub) {
      int ks = kt + sub * 32;
      if (ks < c) {
        bool full = (ks + 32 <= c);          // wave-uniform
        frag8 kf[2];
#pragma unroll
        for (int kh = 0; kh < 2; ++kh) {
          int krow = ks + kh * 16 + m16;
          kf[kh] = *(const frag8*)(qkv + (size_t)(st + krow) * 768 + 256 + head * 32 + quad * 8);
        }
        unsigned pk[2][2][2];  // [qg][khalf][dword]  P^T, bf16-packed
#pragma unroll
        for (int qg = 0; qg < 2; ++qg)
#pragma unroll
          for (int kh = 0; kh < 2; ++kh) {
            f32x4 s = __builtin_amdgcn_mfma_f32_16x16x32_bf16(kf[kh], qf[qg], zz, 0, 0, 0);
            float p[4];
#pragma unroll
            for (int r = 0; r < 4; ++r) p[r] = __expf(s[r] * SCALE);
            if (!full) {
#pragma unroll
              for (int r = 0; r < 4; ++r)
                if (ks + kh * 16 + quad * 4 + r >= c) p[r] = 0.f;
            }
            lp[qg] += (p[0] + p[1]) + (p[2] + p[3]);
            pk[qg][kh][0] = pack2bf(p[0], p[1]);
            pk[qg][kh][1] = pack2bf(p[2], p[3]);
          }
#if HAS_MFMA16
        // PV: A = P^T chunk already in A-frag layout; B = V from Vt (8B reads)
        frag4 vb[2][2];
#pragma unroll
        for (int kh = 0; kh < 2; ++kh)
#pragma unroll
          for (int dh = 0; dh < 2; ++dh)
            vb[kh][dh] = *(const frag4*)&Vt[dh * 16 + m16][sub * 32 + kh * 16 + quad * 4];
#pragma unroll
        for (int qg = 0; qg < 2; ++qg) {
          frag4 pa0 = __builtin_bit_cast(frag4, uint2e{pk[qg][0][0], pk[qg][0][1]});
          frag4 pa1 = __builtin_bit_cast(frag4, uint2e{pk[qg][1][0], pk[qg][1][1]});
#pragma unroll
          for (int dh = 0; dh < 2; ++dh) {
            O[qg][dh] = __builtin_amdgcn_mfma_f32_16x16x16bf16_1k(pa0, vb[0][dh], O[qg][dh], 0, 0, 0);
            O[qg][dh] = __builtin_amdgcn_mfma_f32_16x16x16bf16_1k(pa1, vb[1][dh], O[qg][dh], 0, 0, 0);
          }
        }
#else
        frag8 vf[2];
#pragma unroll
        for (int dh = 0; dh < 2; ++dh)
          vf[dh] = *(const frag8*)&Vt[dh * 16 + m16][sub * 32 + quad * 8];
#pragma unroll
        for (int qg = 0; qg < 2; ++qg) {
          unsigned a0 = __shfl(pk[qg][0][0], sl0), a1 = __shfl(pk[qg][0][1], sl0);
          unsigned a2 = __shfl(pk[qg][0][0], sl1), a3 = __shfl(pk[qg][0][1], sl1);
          unsigned b0 = __shfl(pk[qg][1][0], sl0), b1 = __shfl(pk[qg][1][1], sl0);
          unsigned b2 = __shfl(pk[qg][1][0], sl1), b3 = __shfl(pk[qg][1][1], sl1);
          uint4 pw;
          pw.x = (quad < 2) ? a0 : b0;
          pw.y = (quad < 2) ? a1 : b1;
          pw.z = (quad < 2) ? a2 : b2;
          pw.w = (quad < 2) ? a3 : b3;
          frag8 pf = __builtin_bit_cast(frag8, pw);
#pragma unroll
          for (int dh = 0; dh < 2; ++dh)
            O[qg][dh] = __builtin_amdgcn_mfma_f32_16x16x32_bf16(pf, vf[dh], O[qg][dh], 0, 0, 0);
        }
#endif
      }
    }
    __syncthreads();
  }

  // lp per-lane partial (q = m16); reduce over quads
#pragma unroll
  for (int qg = 0; qg < 2; ++qg) {
    float v = lp[qg];
    v += __shfl_xor(v, 16);
    v += __shfl_xor(v, 32);
    lp[qg] = v;
  }

#pragma unroll
  for (int qg = 0; qg < 2; ++qg)
#pragma unroll
    for (int r = 0; r < 4; ++r) {
      int qrow = qbase + qg * 16 + quad * 4 + r;
      float lsum = __shfl(lp[qg], quad * 4 + r);  // l for this O-row
      if (qrow < c) {
        float inv = 1.f / (lsum + extra);
        unsigned short* op = ctx + (size_t)(st + qrow) * 256 + head * 32;
        op[m16] = f2bf(O[qg][0][r] * inv);
        op[16 + m16] = f2bf(O[qg][1][r] * inv);
      }
    }
}

// --------- BatchNorm apply+ReLU, bnp recomputed per-thread (L1-broadcast) ---------
__global__ __launch_bounds__(256) void k_bn_apply(const unsigned short* __restrict__ h,
                                                  const float* __restrict__ sums,
                                                  const float* __restrict__ gamma,
                                                  const float* __restrict__ beta,
                                                  float* __restrict__ out) {
  size_t i8 = ((size_t)blockIdx.x * 256 + threadIdx.x) * 8;
  int c0 = (int)(i8 & 255);
  ushort8 v = *(const ushort8*)(h + i8);
  float4 o0, o1;
  float res[8];
#pragma unroll
  for (int i = 0; i < 8; ++i) {
    int ch = c0 + i;
    float mean = sums[ch] * (1.0f / NN);
    float var = sums[256 + ch] * (1.0f / NN) - mean * mean;  // biased, ddof=0
    float sc = rsqrtf(var + 1e-5f) * gamma[ch];
    float sh = beta[ch] - mean * sc;
    res[i] = fmaxf(bf2f(v[i]) * sc + sh, 0.f);
  }
  o0.x = res[0]; o0.y = res[1]; o0.z = res[2]; o0.w = res[3];
  o1.x = res[4]; o1.y = res[5]; o1.z = res[6]; o1.w = res[7];
  *(float4*)(out + i8) = o0;
  *(float4*)(out + i8 + 4) = o1;
}

extern "C" void kernel_launch(void* const* d_in, const int* in_sizes, int n_in,
                              void* d_out, int out_size, void* d_ws, size_t ws_size,
                              hipStream_t stream) {
  const float* x      = (const float*)d_in[0];
  const float* spec   = (const float*)d_in[1];
  const float* Ws     = (const float*)d_in[2];
  const float* bs     = (const float*)d_in[3];
  const float* Win    = (const float*)d_in[4];
  const float* b_in   = (const float*)d_in[5];
  const float* Wout   = (const float*)d_in[6];
  const float* b_out  = (const float*)d_in[7];
  const float* gamma  = (const float*)d_in[8];
  const float* beta   = (const float*)d_in[9];
  const int* batch    = (const int*)d_in[10];   // harness passes integers as int32
  float* out = (float*)d_out;

  char* w = (char*)d_ws;
  size_t off = 0;
  auto alloc = [&](size_t bytes) -> void* {
    off = (off + 255) & ~(size_t)255;
    void* p = w + off; off += bytes; return p;
  };
  int* meta             = (int*)alloc(129 * sizeof(int));
  unsigned short* wst   = (unsigned short*)alloc((size_t)4 * 64 * 256 * 2);
  unsigned short* winb  = (unsigned short*)alloc((size_t)768 * 256 * 2);
  unsigned short* woutb = (unsigned short*)alloc((size_t)256 * 256 * 2);
  float* sums           = (float*)alloc(512 * 4);
  unsigned short* h     = (unsigned short*)alloc((size_t)NN * 256 * 2);
  unsigned short* qkv   = (unsigned short*)alloc((size_t)NN * 768 * 2);
  unsigned short* ctx   = (unsigned short*)alloc((size_t)NN * 256 * 2);
  unsigned short* hatt  = (unsigned short*)alloc((size_t)NN * 256 * 2);

  (void)hipMemsetAsync(sums, 0, 512 * 4, stream);
  k_prep<<<1280, 256, 0, stream>>>(Ws, Win, Wout, batch, wst, winb, woutb, meta);
  k_meta2<<<1, 64, 0, stream>>>(meta);
  k_scale<<<dim3(NN / BM, 4), 256, 0, stream>>>(x, spec, wst, bs, h);
  k_lin<768, false, false><<<dim3(NN / BM, 6), 256, 0, stream>>>(h, winb, b_in, qkv, nullptr);
  k_attn_mfma<<<dim3(NB * NHEAD, 8), 256, 0, stream>>>(qkv, meta, ctx);
  k_lin<256, false, true><<<dim3(NN / BM, 2), 256, 0, stream>>>(ctx, woutb, b_out, hatt, sums);
  k_bn_apply<<<NN * 256 / 2048, 256, 0, stream>>>(hatt, sums, gamma, beta, out);
}